// Round 10
// baseline (2752.712 us; speedup 1.0000x reference)
//
#include <hip/hip_runtime.h>

#define BB 8
#define NN 8192
#define KK 6
#define DD 256
#define LL 5
#define NE (BB*NN*KK)       // 393216
#define PLANE (NN*DD)       // 2097152 elems per batch
#define INV6 (1.0f/6.000001f)

typedef unsigned short u16;
typedef __attribute__((ext_vector_type(8))) _Float16 h8;
typedef __attribute__((ext_vector_type(8))) unsigned short us8;
typedef __attribute__((ext_vector_type(4))) float f32x4;

__device__ __forceinline__ u16 f2h(float f){
  union { _Float16 h; u16 u; } c; c.h = (_Float16)f; return c.u;
}
__device__ __forceinline__ float h2f(u16 u){
  union { _Float16 h; u16 u; } c; c.u = u; return (float)c.h;
}

// async global->LDS 16B copy: LDS dest must be wave-uniform base + lane*16
__device__ __forceinline__ void ldscp(const u16* g, u16* l){
  __builtin_amdgcn_global_load_lds(
      (const __attribute__((address_space(1))) void*)g,
      (__attribute__((address_space(3))) void*)l, 16, 0, 0);
}

// ---------------- CSR build ----------------
__global__ void k_count(const int* __restrict__ knn, int* __restrict__ off){
  int e = blockIdx.x*256 + threadIdx.x;
  if(e >= NE) return;
  int b = e / (NN*KK);
  int j = knn[e];
  atomicAdd(&off[b*(NN+1) + 1 + j], 1);
}

__global__ __launch_bounds__(1024) void k_scan(int* __restrict__ offAll){
  __shared__ int lds[1024];
  __shared__ int carry_s;
  int* off = offAll + blockIdx.x*(NN+1);
  const int len = NN+1;
  int t = threadIdx.x;
  if(t==0) carry_s = 0;
  __syncthreads();
  for(int base=0; base<len; base+=1024){
    int x = (base+t < len) ? off[base+t] : 0;
    lds[t] = x; __syncthreads();
    for(int s=1; s<1024; s<<=1){
      int v = (t>=s) ? lds[t-s] : 0;
      __syncthreads();
      lds[t] += v;
      __syncthreads();
    }
    int incl = lds[t];
    int carry = carry_s;
    __syncthreads();
    if(base+t < len) off[base+t] = incl + carry;
    if(t==1023) carry_s = carry + incl;
    __syncthreads();
  }
}

__global__ void k_fill(const int* __restrict__ knn, int* __restrict__ cursor, int* __restrict__ srcE){
  int e = blockIdx.x*256 + threadIdx.x;
  if(e >= NE) return;
  int b = e / (NN*KK);
  int n = (e % (NN*KK)) / KK;
  int j = knn[e];
  int pos = atomicAdd(&cursor[b*(NN+1) + j], 1);
  srcE[(long)b*NN*KK + pos] = n;
}

// ---- weight prep: W fp32 [L][256][N] -> Wt hi/lo fp16 [L][2][N][256] ----
__global__ __launch_bounds__(256) void k_prepw(const float* __restrict__ W, u16* __restrict__ Wt, int N){
  int n = blockIdx.x, l = blockIdx.y, k = threadIdx.x;
  float x = W[((long)l*256 + k)*N + n];
  u16 hb = f2h(x);
  Wt[(((long)l*2 + 0)*N + n)*256 + k] = hb;
  Wt[(((long)l*2 + 1)*N + n)*256 + k] = f2h(x - h2f(hb));
}

// ---------------- embed ----------------
__global__ __launch_bounds__(256) void k_embed(const float* __restrict__ x, const float* __restrict__ ew,
                        const float* __restrict__ eb, float* __restrict__ h){
  int g = blockIdx.x, z = blockIdx.y, d = threadIdx.x;
  const float* xp = x + ((long)z*NN + g)*3;
  h[(long)z*PLANE + (long)g*DD + d] = xp[0]*ew[0*DD+d] + xp[1]*ew[1*DD+d] + xp[2]*ew[2*DD+d] + eb[d];
}

// ---------------- layernorm fp32 -> fp16 single plane (layer-0 only) ----------------
__global__ __launch_bounds__(256) void k_ln(const float* __restrict__ h, const float* __restrict__ g,
                     const float* __restrict__ bia, u16* __restrict__ out){
  long z = blockIdx.y;
  int row = blockIdx.x*4 + (threadIdx.x >> 6);
  int lane = threadIdx.x & 63;
  const float4 x = *(const float4*)(h + z*PLANE + (long)row*DD + lane*4);
  float s  = x.x + x.y + x.z + x.w;
  float s2 = x.x*x.x + x.y*x.y + x.z*x.z + x.w*x.w;
  for(int o=1;o<64;o<<=1){ s += __shfl_xor(s,o); s2 += __shfl_xor(s2,o); }
  float m = s*(1.0f/256.0f);
  float var = s2*(1.0f/256.0f) - m*m;
  float r = rsqrtf(var + 1e-5f);
  const float4 gu = *(const float4*)(g + lane*4);
  const float4 bu = *(const float4*)(bia + lane*4);
  ushort4 o4;
  o4.x = f2h((x.x-m)*r*gu.x + bu.x);
  o4.y = f2h((x.y-m)*r*gu.y + bu.y);
  o4.z = f2h((x.z-m)*r*gu.z + bu.z);
  o4.w = f2h((x.w-m)*r*gu.w + bu.w);
  *(ushort4*)(out + z*PLANE + (long)row*DD + lane*4) = o4;
}

// ---------------- fp16 MFMA GEMM ----------------
// R8-validated: double-buffered stage-early/drain-late K-loop for !BF32
// (MfmaUtil 25->30.8%, FETCH -4MB). MFMA order unchanged -> bit-identical.
template<int BM,int BN,bool ASPLIT,bool BF32,bool BSPLIT>
__global__ __launch_bounds__(256) void k_mgemm(
    const u16* __restrict__ A, long aStride, long aLoOff, int K, int kSplit,
    const void* __restrict__ Bv, long bStride, long bLoOff,
    const float* __restrict__ rowscale, long rsStride,
    const float* __restrict__ bias,
    u16* __restrict__ o0, u16* __restrict__ o1, u16* __restrict__ o2,
    long oStride, int reluMask, long oLoOff,
    float* __restrict__ accOut, long hStride)
{
  constexpr int WM = BM/2, WN = BN/2, MT = WM/16, NT = WN/16;
  constexpr int STG1 = BM*32*(ASPLIT?2:1) + BN*32*(BSPLIT?2:1);
  constexpr int STGT = BF32 ? STG1 : 2*STG1;      // dbuf for !BF32
  constexpr int EPI = (BM==128) ? 32*132*2 : 0;
  constexpr int SM  = (STGT > EPI) ? STGT : EPI;
  __shared__ __align__(16) u16 smem[SM];
  float* epi = (float*)smem;

  const int t = threadIdx.x;
  const int nz = blockIdx.z;
  const long z = nz / kSplit;
  const int chunk = nz % kSplit;
  const int kLen = K / kSplit, kLo = chunk * kLen;
  const int rowTile = blockIdx.x*BM, colTile = blockIdx.y*BN;
  const int l = t & 63, w = t >> 6;
  const int wr = w >> 1, wc = w & 1;
  const int lm = l & 15, kq = l >> 4;

  f32x4 acc[MT][NT];
  #pragma unroll
  for(int mt=0;mt<MT;mt++)
    #pragma unroll
    for(int nt=0;nt<NT;nt++) acc[mt][nt] = (f32x4){0.f,0.f,0.f,0.f};

  if constexpr (!BF32){
    // ---- double-buffered pipelined K-loop (stage-early, drain-late) ----
    auto stageAB = [&](int buf, int k0){
      u16* Ahi_ = smem + (size_t)buf*STG1;
      u16* Alo_ = Ahi_ + BM*32;
      u16* Bhi_ = Ahi_ + BM*32*(ASPLIT?2:1);
      u16* Blo_ = Bhi_ + BN*32;
      {
        constexpr int NCH = BM/64;
        #pragma unroll
        for(int li=0; li<NCH; li++){
          int f = li*256 + t;
          int row = f>>2, c = (f&3)*8;
          const u16* gp = A + z*aStride + (long)(rowTile+row)*K + k0 + c;
          ldscp(gp, &Ahi_[f*8]);
          if constexpr (ASPLIT) ldscp(gp + aLoOff, &Alo_[f*8]);
        }
      }
      {
        constexpr int NCH = BN/64;
        #pragma unroll
        for(int li=0; li<NCH; li++){
          int f = li*256 + t;
          int row = f>>2, c = (f&3)*8;
          const u16* gp = (const u16*)Bv + z*bStride + (long)(colTile+row)*K + k0 + c;
          ldscp(gp, &Bhi_[f*8]);
          if constexpr (BSPLIT) ldscp(gp + bLoOff, &Blo_[f*8]);
        }
      }
    };

    const int nsteps = kLen >> 5;
    stageAB(0, kLo);
    __syncthreads();                 // drain initial stage
    int cur = 0;
    for(int ks=0; ks<nsteps; ++ks){
      if(ks+1 < nsteps) stageAB(cur^1, kLo + ((ks+1)<<5));   // prefetch next
      const u16* Ahi_ = smem + (size_t)cur*STG1;
      const u16* Alo_ = Ahi_ + BM*32;
      const u16* Bhi_ = Ahi_ + BM*32*(ASPLIT?2:1);
      const u16* Blo_ = Bhi_ + BN*32;
      h8 ah[MT], al[MT], bh[NT], bl[NT];
      #pragma unroll
      for(int mt=0;mt<MT;mt++){
        int idx = (wr*WM + mt*16 + lm)*32 + kq*8;
        ah[mt] = *(const h8*)&Ahi_[idx];
        if constexpr (ASPLIT) al[mt] = *(const h8*)&Alo_[idx];
      }
      #pragma unroll
      for(int nt=0;nt<NT;nt++){
        int idx = (wc*WN + nt*16 + lm)*32 + kq*8;
        bh[nt] = *(const h8*)&Bhi_[idx];
        if constexpr (BSPLIT) bl[nt] = *(const h8*)&Blo_[idx];
      }
      #pragma unroll
      for(int mt=0;mt<MT;mt++)
        #pragma unroll
        for(int nt=0;nt<NT;nt++){
          acc[mt][nt] = __builtin_amdgcn_mfma_f32_16x16x32_f16(ah[mt], bh[nt], acc[mt][nt], 0, 0, 0);
          if constexpr (BSPLIT)
            acc[mt][nt] = __builtin_amdgcn_mfma_f32_16x16x32_f16(ah[mt], bl[nt], acc[mt][nt], 0, 0, 0);
          if constexpr (ASPLIT)
            acc[mt][nt] = __builtin_amdgcn_mfma_f32_16x16x32_f16(al[mt], bh[nt], acc[mt][nt], 0, 0, 0);
        }
      __syncthreads();               // single full drain per step, after MFMA
      cur ^= 1;
    }
  } else {
    // ---- legacy single-buffer loop (BF32/w2t path) ----
    u16* Ahi = smem;
    u16* Alo = smem + BM*32;
    u16* Bhi = smem + BM*32*(ASPLIT?2:1);
    for(int k0=kLo; k0<kLo+kLen; k0+=32){
      __syncthreads();
      {
        constexpr int NCH = BM/64;
        #pragma unroll
        for(int li=0; li<NCH; li++){
          int f = li*256 + t;
          int row = f>>2, c = (f&3)*8;
          const u16* gp = A + z*aStride + (long)(rowTile+row)*K + k0 + c;
          ldscp(gp, &Ahi[f*8]);
          if constexpr (ASPLIT) ldscp(gp + aLoOff, &Alo[f*8]);
        }
      }
      {
        constexpr int NCH = BN/64;
        #pragma unroll
        for(int li=0; li<NCH; li++){
          int f = li*256 + t;
          int row = f>>2, c = (f&3)*8;
          const float* src = (const float*)Bv + z*bStride + (long)(colTile+row)*K + k0 + c;
          float4 v0 = ((const float4*)src)[0], v1 = ((const float4*)src)[1];
          us8 hv;
          hv[0]=f2h(v0.x); hv[1]=f2h(v0.y); hv[2]=f2h(v0.z); hv[3]=f2h(v0.w);
          hv[4]=f2h(v1.x); hv[5]=f2h(v1.y); hv[6]=f2h(v1.z); hv[7]=f2h(v1.w);
          *(us8*)&Bhi[f*8] = hv;
        }
      }
      __syncthreads();
      h8 ah[MT], al[MT], bh[NT];
      #pragma unroll
      for(int mt=0;mt<MT;mt++){
        int idx = (wr*WM + mt*16 + lm)*32 + kq*8;
        ah[mt] = *(const h8*)&Ahi[idx];
        if constexpr (ASPLIT) al[mt] = *(const h8*)&Alo[idx];
      }
      #pragma unroll
      for(int nt=0;nt<NT;nt++){
        int idx = (wc*WN + nt*16 + lm)*32 + kq*8;
        bh[nt] = *(const h8*)&Bhi[idx];
      }
      #pragma unroll
      for(int mt=0;mt<MT;mt++)
        #pragma unroll
        for(int nt=0;nt<NT;nt++){
          acc[mt][nt] = __builtin_amdgcn_mfma_f32_16x16x32_f16(ah[mt], bh[nt], acc[mt][nt], 0, 0, 0);
          if constexpr (ASPLIT)
            acc[mt][nt] = __builtin_amdgcn_mfma_f32_16x16x32_f16(al[mt], bh[nt], acc[mt][nt], 0, 0, 0);
        }
    }
  }

  if constexpr (BM == 128){
    const int sec = colTile >> 8;
    u16* osec = (sec==0) ? o0 : ((sec==1) ? o1 : o2);
    const bool relu = (reluMask >> sec) & 1;
    #pragma unroll
    for(int mt=0;mt<MT;mt++){
      __syncthreads();
      #pragma unroll
      for(int r=0;r<4;r++){
        int gm = rowTile + wr*64 + mt*16 + kq*4 + r;
        float sc = rowscale ? rowscale[z*rsStride + gm] : 1.0f;
        int rl = wr*16 + kq*4 + r;
        #pragma unroll
        for(int nt=0;nt<NT;nt++)
          epi[rl*132 + wc*64 + nt*16 + lm] = acc[mt][nt][r]*sc;
      }
      __syncthreads();
      #pragma unroll
      for(int ss=0;ss<2;ss++){
        int s = ss*256 + t;
        int rl = s >> 4, sc8 = (s & 15)*8;
        int gm2 = rowTile + (rl>>4)*64 + mt*16 + (rl & 15);
        float v[8];
        #pragma unroll
        for(int j=0;j<8;j++) v[j] = epi[rl*132 + sc8 + j];
        if(bias){
          const float* bp = bias + colTile + sc8;
          #pragma unroll
          for(int j=0;j<8;j++) v[j] += bp[j];
        }
        if(accOut){
          float* hp = accOut + z*hStride + (long)gm2*256 + colTile + sc8;
          float4 h0 = ((float4*)hp)[0], h1 = ((float4*)hp)[1];
          h0.x += v[0]; h0.y += v[1]; h0.z += v[2]; h0.w += v[3];
          h1.x += v[4]; h1.y += v[5]; h1.z += v[6]; h1.w += v[7];
          ((float4*)hp)[0] = h0; ((float4*)hp)[1] = h1;
        } else {
          us8 o8;
          #pragma unroll
          for(int j=0;j<8;j++){
            float vv = v[j];
            if(relu) vv = fmaxf(vv, 0.f) + 1e-6f;
            o8[j] = f2h(vv);
          }
          *(us8*)(osec + z*oStride + (long)gm2*256 + ((colTile + sc8) & 255)) = o8;
        }
      }
    }
  } else {
    #pragma unroll
    for(int mt=0;mt<MT;mt++){
      #pragma unroll
      for(int r=0;r<4;r++){
        int gm = rowTile + wr*WM + mt*16 + kq*4 + r;
        float sc = rowscale ? rowscale[z*rsStride + gm] : 1.0f;
        if(accOut){
          float* hp = accOut + z*hStride + (long)gm*256;
          if(kSplit > 1){
            #pragma unroll
            for(int nt=0;nt<NT;nt++){
              int gc = colTile + wc*WN + nt*16 + lm;
              atomicAdd(&hp[gc], acc[mt][nt][r]);
            }
          } else {
            #pragma unroll
            for(int nt=0;nt<NT;nt++){
              int gc = colTile + wc*WN + nt*16 + lm;
              hp[gc] += acc[mt][nt][r]*sc + (bias ? bias[gc] : 0.f);
            }
          }
        } else {
          #pragma unroll
          for(int nt=0;nt<NT;nt++){
            int gc = colTile + wc*WN + nt*16 + lm;
            int sec = gc >> 8;
            u16* o = (sec==0) ? o0 : ((sec==1) ? o1 : o2);
            float val = acc[mt][nt][r]*sc + (bias ? bias[gc] : 0.f);
            if((reluMask >> sec) & 1) val = fmaxf(val, 0.f) + 1e-6f;
            if(sec==0 && oLoOff){
              u16* oo = o0 + 2*z*oStride + (long)gm*256 + (gc & 255);
              u16 hb = f2h(val);
              oo[0] = hb;
              oo[oLoOff] = f2h(val - h2f(hb));
            } else {
              o[z*oStride + (long)gm*256 + (gc & 255)] = f2h(val);
            }
          }
        }
      }
    }
  }
}

// ---------------- fused out-projection: GEMM + h RMW + LN / zcalc / head ----------------
// R10 fusion: gatherIn != null (GRF side) -> A = gather(gatherIn)*INV6 computed
// INLINE in the A-prologue (kk-outer, CSR e-pair inner: per-element fp32 chain
// identical to the old k_spmm2 v3 path -> f2h(av*INV6) bit-identical to the
// old T). Kills the v3 half of k_spmm2<1> + T write (32MB) + T read (32MB).
// Block->batch mapping swizzled (batch = lid % C) so each XCD's gather working
// set is ONE batch's plane (4MB = L2), per the R1/R2 locality lesson.
// R9 fusions retained: ksumIn (inline zcalc), headW (inline head).
__global__ __launch_bounds__(256) void k_fusedout(
    const u16* __restrict__ A, const u16* __restrict__ B, long bStride, long bLoOff,
    const u16* __restrict__ gatherIn, const int* __restrict__ offB, const int* __restrict__ srcB,
    const float* __restrict__ rowscale, const float* __restrict__ ksumIn,
    const float* __restrict__ bias,
    float* __restrict__ h,
    const float* __restrict__ lnG, const float* __restrict__ lnB,
    u16* __restrict__ Lout,
    const float* __restrict__ headW, const float* __restrict__ headB,
    float* __restrict__ headOut)
{
  // smem: Bh 256x32 + Bl 256x32 u16 = 32,768B; epilogue 16x260 f32 = 16,640B
  __shared__ __align__(16) u16 smem[16384];
  u16* Bh = smem;
  u16* Bl = smem + 8192;
  float* epi = (float*)smem;

  const int t = threadIdx.x;
  // batch-swizzled block mapping: lid%C = batch -> XCD-local gather set
  const int lid = blockIdx.x + gridDim.x*blockIdx.z;
  const int nbat = gridDim.z;
  const long z = lid % nbat;
  const int rowTile = (lid / nbat)*32;
  const int l = t & 63, w = t >> 6;
  const int wr = w >> 1, wc = w & 1;
  const int lm = l & 15, kq = l >> 4;
  const u16* Bb = B + z*bStride;

  f32x4 acc[8];
  #pragma unroll
  for(int nt=0;nt<8;nt++) acc[nt] = (f32x4){0.f,0.f,0.f,0.f};

  // prologue: lane's A row-fragment for all 8 k-steps (64 fp16 = 32 VGPR)
  h8 areg[8];
  if(gatherIn){
    // inline v3 = gather(v2)*INV6 for this lane's (row, 64-col slice).
    // Per-element accumulation chain identical to the old spmm v3 kernel
    // (e ascending, pairs of 2, tail) -> f2h result bit-identical to old T.
    const u16* vp = gatherIn + z*PLANE;
    const int* off = offB + z*(NN+1);
    const int* sE  = srcB + z*(long)NN*KK;
    int row = rowTile + wr*16 + lm;
    int s0 = off[row], s1 = off[row+1];
    #pragma unroll
    for(int kk=0;kk<8;kk++){
      const int cbase = kq*8 + kk*32;
      float av[8];
      #pragma unroll
      for(int j=0;j<8;j++) av[j]=0.f;
      int e = s0;
      for(; e+1 < s1; e += 2){
        int n0 = sE[e], n1 = sE[e+1];
        us8 v0 = *(const us8*)(vp + (long)n0*DD + cbase);
        us8 v1 = *(const us8*)(vp + (long)n1*DD + cbase);
        #pragma unroll
        for(int j=0;j<8;j++) av[j] += h2f(v0[j]) + h2f(v1[j]);
      }
      if(e < s1){
        int n0 = sE[e];
        us8 v0 = *(const us8*)(vp + (long)n0*DD + cbase);
        #pragma unroll
        for(int j=0;j<8;j++) av[j] += h2f(v0[j]);
      }
      us8 o;
      #pragma unroll
      for(int j=0;j<8;j++) o[j] = f2h(av[j]*INV6);
      areg[kk] = *(h8*)&o;
    }
  } else {
    const u16* arow = A + z*PLANE + (long)(rowTile + wr*16 + lm)*256 + kq*8;
    #pragma unroll
    for(int kk=0;kk<8;kk++) areg[kk] = *(const h8*)(arow + kk*32);
  }

  // fused zcalc: rs = 1/(q . ksum + 1e-6) from A-regs (A = q). Lane holds
  // 64 of the row's 256 elems; reduce over the kq quad (lane bits 4,5).
  float rsv = 0.f;
  if(ksumIn){
    const float* kb = ksumIn + z*DD;
    float s = 0.f;
    #pragma unroll
    for(int kk=0;kk<8;kk++){
      const float4 c0v = *(const float4*)(kb + kq*8 + kk*32);
      const float4 c1v = *(const float4*)(kb + kq*8 + kk*32 + 4);
      s += (float)areg[kk][0]*c0v.x + (float)areg[kk][1]*c0v.y
         + (float)areg[kk][2]*c0v.z + (float)areg[kk][3]*c0v.w
         + (float)areg[kk][4]*c1v.x + (float)areg[kk][5]*c1v.y
         + (float)areg[kk][6]*c1v.z + (float)areg[kk][7]*c1v.w;
    }
    s += __shfl_xor(s, 16);
    s += __shfl_xor(s, 32);
    rsv = 1.0f/(s + 1e-6f);
  }

  #pragma unroll
  for(int kk=0; kk<8; ++kk){
    __syncthreads();
    #pragma unroll
    for(int li=0; li<4; li++){   // B: 256x32 tile per buffer, 4 x 16B per thread
      int f = li*256 + t;
      int row = f>>2, c = (f&3)*8;
      const u16* gp = Bb + (long)row*256 + kk*32 + c;
      ldscp(gp, &Bh[f*8]);
      ldscp(gp + bLoOff, &Bl[f*8]);
    }
    __syncthreads();
    #pragma unroll
    for(int nt=0;nt<8;nt++){
      int idx = (wc*128 + nt*16 + lm)*32 + kq*8;
      const h8 bhf = *(const h8*)&Bh[idx];
      const h8 blf = *(const h8*)&Bl[idx];
      acc[nt] = __builtin_amdgcn_mfma_f32_16x16x32_f16(areg[kk], bhf, acc[nt], 0, 0, 0);
      acc[nt] = __builtin_amdgcn_mfma_f32_16x16x32_f16(areg[kk], blf, acc[nt], 0, 0, 0);
    }
  }

  // epilogue: 2 phases of 16 rows (wave wr==p owns phase p's accumulators)
  #pragma unroll
  for(int p=0;p<2;p++){
    __syncthreads();
    if(wr == p){   // wave-uniform guard (wr constant per wave) -> shfl safe
      #pragma unroll
      for(int r=0;r<4;r++){
        int rl = kq*4 + r;
        int gm = rowTile + p*16 + rl;
        float sc;
        if(ksumIn) sc = __shfl(rsv, kq*4 + r);   // rs of row p*16+kq*4+r
        else       sc = rowscale ? rowscale[z*NN + gm] : 1.0f;
        #pragma unroll
        for(int nt=0;nt<8;nt++)
          epi[rl*260 + wc*128 + nt*16 + lm] = acc[nt][r]*sc;
      }
    }
    __syncthreads();
    // store phase: one 64-lane wave per row, float4 per lane (k_ln-identical)
    #pragma unroll
    for(int ss=0;ss<4;ss++){
      int s = ss*256 + t;
      int rl = s >> 6;               // 0..15 (uniform per wave)
      int c4 = (s & 63)*4;           // lane*4
      int gm = rowTile + p*16 + rl;
      float4 e = *(float4*)&epi[rl*260 + c4];
      float4 x;
      x.x = e.x + bias[c4+0];
      x.y = e.y + bias[c4+1];
      x.z = e.z + bias[c4+2];
      x.w = e.w + bias[c4+3];
      float* hp = h + z*PLANE + (long)gm*256 + c4;
      float4 h0 = *(float4*)hp;
      x.x += h0.x; x.y += h0.y; x.z += h0.z; x.w += h0.w;
      *(float4*)hp = x;
      if(lnG){
        float sA = x.x + x.y + x.z + x.w;
        float s2 = x.x*x.x + x.y*x.y + x.z*x.z + x.w*x.w;
        for(int o=1;o<64;o<<=1){ sA += __shfl_xor(sA,o); s2 += __shfl_xor(s2,o); }
        float m = sA*(1.0f/256.0f);
        float var = s2*(1.0f/256.0f) - m*m;
        float rr = rsqrtf(var + 1e-5f);
        const float4 gu = *(const float4*)(lnG + c4);
        const float4 bu = *(const float4*)(lnB + c4);
        ushort4 o4;
        o4.x = f2h((x.x-m)*rr*gu.x + bu.x);
        o4.y = f2h((x.y-m)*rr*gu.y + bu.y);
        o4.z = f2h((x.z-m)*rr*gu.z + bu.z);
        o4.w = f2h((x.w-m)*rr*gu.w + bu.w);
        *(ushort4*)(Lout + z*PLANE + (long)gm*256 + c4) = o4;
      } else if(headW){
        // fused head: identical reduction/code-path as the old k_head
        int d0 = c4;
        float a0 = x.x*headW[(d0+0)*3+0] + x.y*headW[(d0+1)*3+0] + x.z*headW[(d0+2)*3+0] + x.w*headW[(d0+3)*3+0];
        float a1 = x.x*headW[(d0+0)*3+1] + x.y*headW[(d0+1)*3+1] + x.z*headW[(d0+2)*3+1] + x.w*headW[(d0+3)*3+1];
        float a2 = x.x*headW[(d0+0)*3+2] + x.y*headW[(d0+1)*3+2] + x.z*headW[(d0+2)*3+2] + x.w*headW[(d0+3)*3+2];
        for(int o=1;o<64;o<<=1){
          a0 += __shfl_xor(a0,o); a1 += __shfl_xor(a1,o); a2 += __shfl_xor(a2,o);
        }
        if((t & 63)==0){
          float* op = headOut + ((long)z*NN + gm)*3;
          op[0] = a0 + headB[0];
          op[1] = a1 + headB[1];
          op[2] = a2 + headB[2];
        }
      }
    }
  }
}

// ------------- fused k+v spmm gather (fp16 planes, fp32 accum) -------------
// MODE 0: k+v gather+store, D-SPLIT via blockIdx.z (dhalf). Per-XCD-phase read
//   working set = k-half (2MB) + v-half (2MB) = 4MB = one XCD L2.
// MODE 1 (R10: rowdot only): rs = (q . gather(k))*INV6, full-D. The v3 half
//   moved into k_fusedout's gather prologue.
template<int MODE>
__global__ __launch_bounds__(256) void k_spmm2(
    const u16* __restrict__ kin, const u16* __restrict__ vin,
    const int* __restrict__ offB, const int* __restrict__ srcB,
    u16* __restrict__ kout, u16* __restrict__ vout,
    const u16* __restrict__ q, float* __restrict__ rs){
  long z = blockIdx.x;
  const int* off = offB + z*(NN+1);
  const int* sE  = srcB + z*(long)NN*KK;

  if constexpr (MODE == 0){
    const u16* kp = kin + z*PLANE;
    const u16* vp = vin + z*PLANE;
    int row = blockIdx.y*16 + (threadIdx.x >> 4);
    int d8 = blockIdx.z*128 + (threadIdx.x & 15)*8;
    int s0 = off[row], s1 = off[row+1];
    float ak[8], av[8];
    #pragma unroll
    for(int j=0;j<8;j++){ ak[j]=0.f; av[j]=0.f; }
    int e = s0;
    for(; e+1 < s1; e += 2){
      int n0 = sE[e], n1 = sE[e+1];
      us8 k0 = *(const us8*)(kp + (long)n0*DD + d8);
      us8 k1 = *(const us8*)(kp + (long)n1*DD + d8);
      us8 v0 = *(const us8*)(vp + (long)n0*DD + d8);
      us8 v1 = *(const us8*)(vp + (long)n1*DD + d8);
      #pragma unroll
      for(int j=0;j<8;j++){
        ak[j] += h2f(k0[j]) + h2f(k1[j]);
        av[j] += h2f(v0[j]) + h2f(v1[j]);
      }
    }
    if(e < s1){
      int n0 = sE[e];
      us8 k0 = *(const us8*)(kp + (long)n0*DD + d8);
      us8 v0 = *(const us8*)(vp + (long)n0*DD + d8);
      #pragma unroll
      for(int j=0;j<8;j++){ ak[j] += h2f(k0[j]); av[j] += h2f(v0[j]); }
    }
    us8 ok, ov;
    #pragma unroll
    for(int j=0;j<8;j++){ ok[j] = f2h(ak[j]*INV6); ov[j] = f2h(av[j]*INV6); }
    *(us8*)(kout + z*PLANE + (long)row*DD + d8) = ok;
    *(us8*)(vout + z*PLANE + (long)row*DD + d8) = ov;
  } else {
    // rowdot: full-D k-gather, dot with q (numerics identical to old MODE1 z=0)
    const u16* kp = kin + z*PLANE;
    int row = blockIdx.y*8 + (threadIdx.x >> 5);
    int l32 = threadIdx.x & 31;
    int d8 = l32*8;
    int s0 = off[row], s1 = off[row+1];
    float ak[8];
    #pragma unroll
    for(int j=0;j<8;j++) ak[j]=0.f;
    int e = s0;
    for(; e+1 < s1; e += 2){
      int n0 = sE[e], n1 = sE[e+1];
      us8 k0 = *(const us8*)(kp + (long)n0*DD + d8);
      us8 k1 = *(const us8*)(kp + (long)n1*DD + d8);
      #pragma unroll
      for(int j=0;j<8;j++) ak[j] += h2f(k0[j]) + h2f(k1[j]);
    }
    if(e < s1){
      int n0 = sE[e];
      us8 k0 = *(const us8*)(kp + (long)n0*DD + d8);
      #pragma unroll
      for(int j=0;j<8;j++) ak[j] += h2f(k0[j]);
    }
    us8 qv = *(const us8*)(q + z*PLANE + (long)row*DD + d8);
    float s = 0.f;
    #pragma unroll
    for(int j=0;j<8;j++) s += h2f(qv[j]) * ak[j];
    for(int o=1;o<32;o<<=1) s += __shfl_xor(s,o);
    if(l32==0) rs[z*NN + row] = s*INV6;
  }
}

// ---- dual transpose fp16 [8192][256] -> [256][8192] + fused ksum ----
// R9: k tensor (even zz) also accumulates ksum[d] = sum_n k[n][d] from the
// transpose-read registers: 16-elem per-thread partial, quad shuffle-reduce,
// one atomicAdd per 64-row column partial (device-scope). Replaces k_ksum.
__global__ __launch_bounds__(256) void k_transp2(
    const u16* __restrict__ in0, u16* __restrict__ out0,
    const u16* __restrict__ in1, u16* __restrict__ out1,
    float* __restrict__ ksum){
  __shared__ u16 tile[64][72];
  int zz = blockIdx.z;
  long z = zz >> 1;
  const u16* ip = ((zz & 1) ? in1 : in0) + z*PLANE;
  u16* op = ((zz & 1) ? out1 : out0) + z*PLANE;
  int r0 = blockIdx.x*64, c0 = blockIdx.y*64;
  int t = threadIdx.x;
  {
    int r = t>>2, cg = (t&3)*16;
    *(us8*)&tile[r][cg]   = *(const us8*)(ip + (long)(r0+r)*DD + c0 + cg);
    *(us8*)&tile[r][cg+8] = *(const us8*)(ip + (long)(r0+r)*DD + c0 + cg + 8);
  }
  __syncthreads();
  {
    int c = t>>2, rg = t&3;
    us8 a, b;
    #pragma unroll
    for(int j=0;j<8;j++){ a[j] = tile[rg*16+j][c]; b[j] = tile[rg*16+8+j][c]; }
    u16* dst = op + (long)(c0+c)*NN + r0 + rg*16;
    *(us8*)dst = a; *(us8*)(dst+8) = b;
    if((zz & 1)==0){
      float p = 0.f;
      #pragma unroll
      for(int j=0;j<8;j++) p += h2f(a[j]) + h2f(b[j]);
      p += __shfl_xor(p, 1);
      p += __shfl_xor(p, 2);
      if(rg == 0) atomicAdd(&ksum[z*DD + c0 + c], p);
    }
  }
}

struct Carve {
  float *h; u16 *L,*Q,*Bp,*Cp,*T;
  float *kvf; u16 *w2t;
  float *ksum,*rs;
  int *off,*cursor,*srcE;
  u16 *wt_gqkv,*wt_aqkv,*wt_gout,*wt_aout;
  size_t total;
};

static Carve carve(char* base, int C){
  Carve c;
  size_t cur = 0;
  auto bump = [&](size_t bytes)->char*{
    char* p = base ? base + cur : (char*)0;
    cur += (bytes + 255) & ~(size_t)255;
    return p;
  };
  c.h    = (float*)bump((size_t)C*PLANE*4);
  c.L    = (u16*)bump((size_t)C*PLANE*2);   // LN out / hop pong / kT
  c.Q    = (u16*)bump((size_t)C*PLANE*2);
  c.Bp   = (u16*)bump((size_t)C*PLANE*2);   // k
  c.Cp   = (u16*)bump((size_t)C*PLANE*2);   // v
  c.T    = (u16*)bump((size_t)C*PLANE*2);   // hop pong / vT
  c.kvf  = (float*)bump((size_t)C*DD*DD*4);
  c.w2t  = (u16*)bump((size_t)C*2*DD*DD*2); // split pair
  c.ksum = (float*)bump((size_t)C*DD*4);
  c.rs   = (float*)bump((size_t)C*NN*4);
  c.off  = (int*)bump((size_t)BB*(NN+1)*4);
  c.cursor=(int*)bump((size_t)BB*(NN+1)*4);
  c.srcE = (int*)bump((size_t)NE*4);
  c.wt_gqkv = (u16*)bump((size_t)LL*2*768*256*2);
  c.wt_aqkv = (u16*)bump((size_t)LL*2*768*256*2);
  c.wt_gout = (u16*)bump((size_t)LL*2*256*256*2);
  c.wt_aout = (u16*)bump((size_t)LL*2*256*256*2);
  c.total = cur;
  return c;
}

extern "C" void kernel_launch(void* const* d_in, const int* in_sizes, int n_in,
                              void* d_out, int out_size, void* d_ws, size_t ws_size,
                              hipStream_t stream)
{
  const float* x        = (const float*)d_in[0];
  const int*   knn      = (const int*)d_in[1];
  const float* emb_w    = (const float*)d_in[2];
  const float* emb_b    = (const float*)d_in[3];
  const float* norm_g   = (const float*)d_in[4];
  const float* norm_b   = (const float*)d_in[5];
  const float* grf_qkv  = (const float*)d_in[6];
  const float* grf_outw = (const float*)d_in[7];
  const float* grf_outb = (const float*)d_in[8];
  const float* attn_qkv = (const float*)d_in[9];
  const float* attn_outw= (const float*)d_in[10];
  const float* attn_outb= (const float*)d_in[11];
  const float* head_w   = (const float*)d_in[12];
  const float* head_b   = (const float*)d_in[13];
  float* out = (float*)d_out;

  int C = 1;
  for(int cc=BB; cc>=1; cc>>=1){ if(carve(nullptr, cc).total <= ws_size){ C = cc; break; } }
  Carve ws = carve((char*)d_ws, C);

  // ---- weight prep (hi/lo fp16, transposed to [N][K]) ----
  k_prepw<<<dim3(768, LL), 256, 0, stream>>>(grf_qkv,  ws.wt_gqkv, 768);
  k_prepw<<<dim3(768, LL), 256, 0, stream>>>(attn_qkv, ws.wt_aqkv, 768);
  k_prepw<<<dim3(256, LL), 256, 0, stream>>>(grf_outw, ws.wt_gout, 256);
  k_prepw<<<dim3(256, LL), 256, 0, stream>>>(attn_outw,ws.wt_aout, 256);

  // ---- CSR build for all batches ----
  hipMemsetAsync(ws.off, 0, (size_t)BB*(NN+1)*sizeof(int), stream);
  k_count<<<dim3((NE+255)/256), 256, 0, stream>>>(knn, ws.off);
  k_scan<<<dim3(BB), 1024, 0, stream>>>(ws.off);
  hipMemcpyAsync(ws.cursor, ws.off, (size_t)BB*(NN+1)*sizeof(int), hipMemcpyDeviceToDevice, stream);
  k_fill<<<dim3((NE+255)/256), 256, 0, stream>>>(knn, ws.cursor, ws.srcE);

  const long PL = PLANE;
  for(int b0=0; b0<BB; b0+=C){
    const int* offB  = ws.off  + (long)b0*(NN+1);
    const int* srcB  = ws.srcE + (long)b0*NN*KK;

    k_embed<<<dim3(NN, C), 256, 0, stream>>>(x + (long)b0*NN*3, emb_w, emb_b, ws.h);
    k_ln<<<dim3(NN/4, C), 256, 0, stream>>>(ws.h, norm_g, norm_b, ws.L);

    for(int i=0; i<LL; i++){
      // ===== GRF sublayer =====
      k_mgemm<128,128,false,false,true><<<dim3(64, 6, C), 256, 0, stream>>>(
          ws.L, PL, 0, 256, 1,
          ws.wt_gqkv + (long)i*2*768*256, 0, (long)768*256,
          nullptr, 0, nullptr,
          ws.Q, ws.Bp, ws.Cp, PL, 0, 0, nullptr, 0);
      // hops: (Bp,Cp)->(L,T)->(Bp,Cp); rowdot rs = (q . gather(k3))*INV6;
      // v3 gather fused into k_fusedout's A-prologue (reads Cp directly)
      k_spmm2<0><<<dim3(C, NN/16, 2), 256, 0, stream>>>(ws.Bp, ws.Cp, offB, srcB, ws.L, ws.T, nullptr, nullptr);
      k_spmm2<0><<<dim3(C, NN/16, 2), 256, 0, stream>>>(ws.L,  ws.T,  offB, srcB, ws.Bp, ws.Cp, nullptr, nullptr);
      k_spmm2<1><<<dim3(C, NN/8), 256, 0, stream>>>(ws.Bp, nullptr, offB, srcB, nullptr, nullptr, ws.Q, ws.rs);
      // h += (rs * gather(Cp)*INV6) @ grf_outw + grf_outb ; fused LN -> L
      k_fusedout<<<dim3(NN/32, 1, C), 256, 0, stream>>>(
          nullptr, ws.wt_gout + (long)i*2*256*256, 0, (long)256*256,
          ws.Cp, offB, srcB,
          ws.rs, nullptr, grf_outb + (long)i*DD, ws.h,
          norm_g + (2*i+1)*DD, norm_b + (2*i+1)*DD, ws.L,
          nullptr, nullptr, nullptr);

      // ===== linear attention sublayer =====
      k_mgemm<128,128,false,false,true><<<dim3(64, 6, C), 256, 0, stream>>>(
          ws.L, PL, 0, 256, 1,
          ws.wt_aqkv + (long)i*2*768*256, 0, (long)768*256,
          nullptr, 0, nullptr,
          ws.Q, ws.Bp, ws.Cp, PL, 3 /* relu+1e-6 on q,k */, 0, nullptr, 0);
      // kT = Bp^T -> L ; vT = Cp^T -> T ; ksum fused (atomics)
      hipMemsetAsync(ws.ksum, 0, (size_t)C*DD*sizeof(float), stream);
      k_transp2<<<dim3(NN/64, DD/64, 2*C), 256, 0, stream>>>(ws.Bp, ws.L, ws.Cp, ws.T, ws.ksum);
      // kv[d][e] = sum_n kT[d][n] * vT[e][n]  (split-K=8, atomic fp32)
      hipMemsetAsync(ws.kvf, 0, (size_t)C*DD*DD*sizeof(float), stream);
      k_mgemm<64,64,false,false,false><<<dim3(4, 4, C*8), 256, 0, stream>>>(
          ws.L, PL, 0, NN, 8,
          ws.T, PL, 0,
          nullptr, 0, nullptr,
          nullptr, nullptr, nullptr, 0, 0, 0, ws.kvf, (long)DD*DD);
      // w2t[n][d] = sum_e WoutT[n][e](split) * kv[d][e]  -> split fp16 pair
      k_mgemm<64,64,true,true,false><<<dim3(4, 4, C), 256, 0, stream>>>(
          ws.wt_aout + (long)i*2*256*256, 0, (long)256*256, 256, 1,
          ws.kvf, (long)DD*DD, 0,
          nullptr, 0, nullptr,
          ws.w2t, nullptr, nullptr, (long)DD*DD, 0, (long)DD*DD,
          nullptr, 0);
      // h += (z*q) @ w2 + attn_outb ; rs inline from ksum; fused LN -> L,
      // or (last layer) fused head -> out
      const float* g2 = (i==LL-1) ? nullptr : norm_g + (2*i+2)*DD;
      const float* b2 = (i==LL-1) ? nullptr : norm_b + (2*i+2)*DD;
      k_fusedout<<<dim3(NN/32, 1, C), 256, 0, stream>>>(
          ws.Q, ws.w2t, 2L*DD*DD, (long)DD*DD,
          nullptr, nullptr, nullptr,
          nullptr, ws.ksum, attn_outb + (long)i*DD, ws.h,
          g2, b2, ws.L,
          (i==LL-1) ? head_w : nullptr,
          (i==LL-1) ? head_b : nullptr,
          (i==LL-1) ? (out + (long)b0*NN*3) : nullptr);
    }
  }
}

// Round 11
// 2455.451 us; speedup vs baseline: 1.1211x; 1.1211x over previous
//
#include <hip/hip_runtime.h>

#define BB 8
#define NN 8192
#define KK 6
#define DD 256
#define LL 5
#define NE (BB*NN*KK)       // 393216
#define PLANE (NN*DD)       // 2097152 elems per batch
#define INV6 (1.0f/6.000001f)

typedef unsigned short u16;
typedef __attribute__((ext_vector_type(8))) _Float16 h8;
typedef __attribute__((ext_vector_type(8))) unsigned short us8;
typedef __attribute__((ext_vector_type(4))) float f32x4;

__device__ __forceinline__ u16 f2h(float f){
  union { _Float16 h; u16 u; } c; c.h = (_Float16)f; return c.u;
}
__device__ __forceinline__ float h2f(u16 u){
  union { _Float16 h; u16 u; } c; c.u = u; return (float)c.h;
}

// async global->LDS 16B copy: LDS dest must be wave-uniform base + lane*16
__device__ __forceinline__ void ldscp(const u16* g, u16* l){
  __builtin_amdgcn_global_load_lds(
      (const __attribute__((address_space(1))) void*)g,
      (__attribute__((address_space(3))) void*)l, 16, 0, 0);
}

// ---------------- CSR build ----------------
__global__ void k_count(const int* __restrict__ knn, int* __restrict__ off){
  int e = blockIdx.x*256 + threadIdx.x;
  if(e >= NE) return;
  int b = e / (NN*KK);
  int j = knn[e];
  atomicAdd(&off[b*(NN+1) + 1 + j], 1);
}

__global__ __launch_bounds__(1024) void k_scan(int* __restrict__ offAll){
  __shared__ int lds[1024];
  __shared__ int carry_s;
  int* off = offAll + blockIdx.x*(NN+1);
  const int len = NN+1;
  int t = threadIdx.x;
  if(t==0) carry_s = 0;
  __syncthreads();
  for(int base=0; base<len; base+=1024){
    int x = (base+t < len) ? off[base+t] : 0;
    lds[t] = x; __syncthreads();
    for(int s=1; s<1024; s<<=1){
      int v = (t>=s) ? lds[t-s] : 0;
      __syncthreads();
      lds[t] += v;
      __syncthreads();
    }
    int incl = lds[t];
    int carry = carry_s;
    __syncthreads();
    if(base+t < len) off[base+t] = incl + carry;
    if(t==1023) carry_s = carry + incl;
    __syncthreads();
  }
}

__global__ void k_fill(const int* __restrict__ knn, int* __restrict__ cursor, int* __restrict__ srcE){
  int e = blockIdx.x*256 + threadIdx.x;
  if(e >= NE) return;
  int b = e / (NN*KK);
  int n = (e % (NN*KK)) / KK;
  int j = knn[e];
  int pos = atomicAdd(&cursor[b*(NN+1) + j], 1);
  srcE[(long)b*NN*KK + pos] = n;
}

// ---- weight prep: W fp32 [L][256][N] -> Wt hi/lo fp16 [L][2][N][256] ----
__global__ __launch_bounds__(256) void k_prepw(const float* __restrict__ W, u16* __restrict__ Wt, int N){
  int n = blockIdx.x, l = blockIdx.y, k = threadIdx.x;
  float x = W[((long)l*256 + k)*N + n];
  u16 hb = f2h(x);
  Wt[(((long)l*2 + 0)*N + n)*256 + k] = hb;
  Wt[(((long)l*2 + 1)*N + n)*256 + k] = f2h(x - h2f(hb));
}

// ---------------- embed ----------------
__global__ __launch_bounds__(256) void k_embed(const float* __restrict__ x, const float* __restrict__ ew,
                        const float* __restrict__ eb, float* __restrict__ h){
  int g = blockIdx.x, z = blockIdx.y, d = threadIdx.x;
  const float* xp = x + ((long)z*NN + g)*3;
  h[(long)z*PLANE + (long)g*DD + d] = xp[0]*ew[0*DD+d] + xp[1]*ew[1*DD+d] + xp[2]*ew[2*DD+d] + eb[d];
}

// ---------------- layernorm fp32 -> fp16 single plane (layer-0 only) ----------------
__global__ __launch_bounds__(256) void k_ln(const float* __restrict__ h, const float* __restrict__ g,
                     const float* __restrict__ bia, u16* __restrict__ out){
  long z = blockIdx.y;
  int row = blockIdx.x*4 + (threadIdx.x >> 6);
  int lane = threadIdx.x & 63;
  const float4 x = *(const float4*)(h + z*PLANE + (long)row*DD + lane*4);
  float s  = x.x + x.y + x.z + x.w;
  float s2 = x.x*x.x + x.y*x.y + x.z*x.z + x.w*x.w;
  for(int o=1;o<64;o<<=1){ s += __shfl_xor(s,o); s2 += __shfl_xor(s2,o); }
  float m = s*(1.0f/256.0f);
  float var = s2*(1.0f/256.0f) - m*m;
  float r = rsqrtf(var + 1e-5f);
  const float4 gu = *(const float4*)(g + lane*4);
  const float4 bu = *(const float4*)(bia + lane*4);
  ushort4 o4;
  o4.x = f2h((x.x-m)*r*gu.x + bu.x);
  o4.y = f2h((x.y-m)*r*gu.y + bu.y);
  o4.z = f2h((x.z-m)*r*gu.z + bu.z);
  o4.w = f2h((x.w-m)*r*gu.w + bu.w);
  *(ushort4*)(out + z*PLANE + (long)row*DD + lane*4) = o4;
}

// ---------------- fp16 MFMA GEMM ----------------
// R8-validated: double-buffered stage-early/drain-late K-loop for !BF32
// (MfmaUtil 25->30.8%, FETCH -4MB). MFMA order unchanged -> bit-identical.
template<int BM,int BN,bool ASPLIT,bool BF32,bool BSPLIT>
__global__ __launch_bounds__(256) void k_mgemm(
    const u16* __restrict__ A, long aStride, long aLoOff, int K, int kSplit,
    const void* __restrict__ Bv, long bStride, long bLoOff,
    const float* __restrict__ rowscale, long rsStride,
    const float* __restrict__ bias,
    u16* __restrict__ o0, u16* __restrict__ o1, u16* __restrict__ o2,
    long oStride, int reluMask, long oLoOff,
    float* __restrict__ accOut, long hStride)
{
  constexpr int WM = BM/2, WN = BN/2, MT = WM/16, NT = WN/16;
  constexpr int STG1 = BM*32*(ASPLIT?2:1) + BN*32*(BSPLIT?2:1);
  constexpr int STGT = BF32 ? STG1 : 2*STG1;      // dbuf for !BF32
  constexpr int EPI = (BM==128) ? 32*132*2 : 0;
  constexpr int SM  = (STGT > EPI) ? STGT : EPI;
  __shared__ __align__(16) u16 smem[SM];
  float* epi = (float*)smem;

  const int t = threadIdx.x;
  const int nz = blockIdx.z;
  const long z = nz / kSplit;
  const int chunk = nz % kSplit;
  const int kLen = K / kSplit, kLo = chunk * kLen;
  const int rowTile = blockIdx.x*BM, colTile = blockIdx.y*BN;
  const int l = t & 63, w = t >> 6;
  const int wr = w >> 1, wc = w & 1;
  const int lm = l & 15, kq = l >> 4;

  f32x4 acc[MT][NT];
  #pragma unroll
  for(int mt=0;mt<MT;mt++)
    #pragma unroll
    for(int nt=0;nt<NT;nt++) acc[mt][nt] = (f32x4){0.f,0.f,0.f,0.f};

  if constexpr (!BF32){
    // ---- double-buffered pipelined K-loop (stage-early, drain-late) ----
    auto stageAB = [&](int buf, int k0){
      u16* Ahi_ = smem + (size_t)buf*STG1;
      u16* Alo_ = Ahi_ + BM*32;
      u16* Bhi_ = Ahi_ + BM*32*(ASPLIT?2:1);
      u16* Blo_ = Bhi_ + BN*32;
      {
        constexpr int NCH = BM/64;
        #pragma unroll
        for(int li=0; li<NCH; li++){
          int f = li*256 + t;
          int row = f>>2, c = (f&3)*8;
          const u16* gp = A + z*aStride + (long)(rowTile+row)*K + k0 + c;
          ldscp(gp, &Ahi_[f*8]);
          if constexpr (ASPLIT) ldscp(gp + aLoOff, &Alo_[f*8]);
        }
      }
      {
        constexpr int NCH = BN/64;
        #pragma unroll
        for(int li=0; li<NCH; li++){
          int f = li*256 + t;
          int row = f>>2, c = (f&3)*8;
          const u16* gp = (const u16*)Bv + z*bStride + (long)(colTile+row)*K + k0 + c;
          ldscp(gp, &Bhi_[f*8]);
          if constexpr (BSPLIT) ldscp(gp + bLoOff, &Blo_[f*8]);
        }
      }
    };

    const int nsteps = kLen >> 5;
    stageAB(0, kLo);
    __syncthreads();                 // drain initial stage
    int cur = 0;
    for(int ks=0; ks<nsteps; ++ks){
      if(ks+1 < nsteps) stageAB(cur^1, kLo + ((ks+1)<<5));   // prefetch next
      const u16* Ahi_ = smem + (size_t)cur*STG1;
      const u16* Alo_ = Ahi_ + BM*32;
      const u16* Bhi_ = Ahi_ + BM*32*(ASPLIT?2:1);
      const u16* Blo_ = Bhi_ + BN*32;
      h8 ah[MT], al[MT], bh[NT], bl[NT];
      #pragma unroll
      for(int mt=0;mt<MT;mt++){
        int idx = (wr*WM + mt*16 + lm)*32 + kq*8;
        ah[mt] = *(const h8*)&Ahi_[idx];
        if constexpr (ASPLIT) al[mt] = *(const h8*)&Alo_[idx];
      }
      #pragma unroll
      for(int nt=0;nt<NT;nt++){
        int idx = (wc*WN + nt*16 + lm)*32 + kq*8;
        bh[nt] = *(const h8*)&Bhi_[idx];
        if constexpr (BSPLIT) bl[nt] = *(const h8*)&Blo_[idx];
      }
      #pragma unroll
      for(int mt=0;mt<MT;mt++)
        #pragma unroll
        for(int nt=0;nt<NT;nt++){
          acc[mt][nt] = __builtin_amdgcn_mfma_f32_16x16x32_f16(ah[mt], bh[nt], acc[mt][nt], 0, 0, 0);
          if constexpr (BSPLIT)
            acc[mt][nt] = __builtin_amdgcn_mfma_f32_16x16x32_f16(ah[mt], bl[nt], acc[mt][nt], 0, 0, 0);
          if constexpr (ASPLIT)
            acc[mt][nt] = __builtin_amdgcn_mfma_f32_16x16x32_f16(al[mt], bh[nt], acc[mt][nt], 0, 0, 0);
        }
      __syncthreads();               // single full drain per step, after MFMA
      cur ^= 1;
    }
  } else {
    // ---- legacy single-buffer loop (BF32/w2t path) ----
    u16* Ahi = smem;
    u16* Alo = smem + BM*32;
    u16* Bhi = smem + BM*32*(ASPLIT?2:1);
    for(int k0=kLo; k0<kLo+kLen; k0+=32){
      __syncthreads();
      {
        constexpr int NCH = BM/64;
        #pragma unroll
        for(int li=0; li<NCH; li++){
          int f = li*256 + t;
          int row = f>>2, c = (f&3)*8;
          const u16* gp = A + z*aStride + (long)(rowTile+row)*K + k0 + c;
          ldscp(gp, &Ahi[f*8]);
          if constexpr (ASPLIT) ldscp(gp + aLoOff, &Alo[f*8]);
        }
      }
      {
        constexpr int NCH = BN/64;
        #pragma unroll
        for(int li=0; li<NCH; li++){
          int f = li*256 + t;
          int row = f>>2, c = (f&3)*8;
          const float* src = (const float*)Bv + z*bStride + (long)(colTile+row)*K + k0 + c;
          float4 v0 = ((const float4*)src)[0], v1 = ((const float4*)src)[1];
          us8 hv;
          hv[0]=f2h(v0.x); hv[1]=f2h(v0.y); hv[2]=f2h(v0.z); hv[3]=f2h(v0.w);
          hv[4]=f2h(v1.x); hv[5]=f2h(v1.y); hv[6]=f2h(v1.z); hv[7]=f2h(v1.w);
          *(us8*)&Bhi[f*8] = hv;
        }
      }
      __syncthreads();
      h8 ah[MT], al[MT], bh[NT];
      #pragma unroll
      for(int mt=0;mt<MT;mt++){
        int idx = (wr*WM + mt*16 + lm)*32 + kq*8;
        ah[mt] = *(const h8*)&Ahi[idx];
        if constexpr (ASPLIT) al[mt] = *(const h8*)&Alo[idx];
      }
      #pragma unroll
      for(int nt=0;nt<NT;nt++){
        int idx = (wc*WN + nt*16 + lm)*32 + kq*8;
        bh[nt] = *(const h8*)&Bhi[idx];
      }
      #pragma unroll
      for(int mt=0;mt<MT;mt++)
        #pragma unroll
        for(int nt=0;nt<NT;nt++){
          acc[mt][nt] = __builtin_amdgcn_mfma_f32_16x16x32_f16(ah[mt], bh[nt], acc[mt][nt], 0, 0, 0);
          if constexpr (ASPLIT)
            acc[mt][nt] = __builtin_amdgcn_mfma_f32_16x16x32_f16(al[mt], bh[nt], acc[mt][nt], 0, 0, 0);
        }
    }
  }

  if constexpr (BM == 128){
    const int sec = colTile >> 8;
    u16* osec = (sec==0) ? o0 : ((sec==1) ? o1 : o2);
    const bool relu = (reluMask >> sec) & 1;
    #pragma unroll
    for(int mt=0;mt<MT;mt++){
      __syncthreads();
      #pragma unroll
      for(int r=0;r<4;r++){
        int gm = rowTile + wr*64 + mt*16 + kq*4 + r;
        float sc = rowscale ? rowscale[z*rsStride + gm] : 1.0f;
        int rl = wr*16 + kq*4 + r;
        #pragma unroll
        for(int nt=0;nt<NT;nt++)
          epi[rl*132 + wc*64 + nt*16 + lm] = acc[mt][nt][r]*sc;
      }
      __syncthreads();
      #pragma unroll
      for(int ss=0;ss<2;ss++){
        int s = ss*256 + t;
        int rl = s >> 4, sc8 = (s & 15)*8;
        int gm2 = rowTile + (rl>>4)*64 + mt*16 + (rl & 15);
        float v[8];
        #pragma unroll
        for(int j=0;j<8;j++) v[j] = epi[rl*132 + sc8 + j];
        if(bias){
          const float* bp = bias + colTile + sc8;
          #pragma unroll
          for(int j=0;j<8;j++) v[j] += bp[j];
        }
        if(accOut){
          float* hp = accOut + z*hStride + (long)gm2*256 + colTile + sc8;
          float4 h0 = ((float4*)hp)[0], h1 = ((float4*)hp)[1];
          h0.x += v[0]; h0.y += v[1]; h0.z += v[2]; h0.w += v[3];
          h1.x += v[4]; h1.y += v[5]; h1.z += v[6]; h1.w += v[7];
          ((float4*)hp)[0] = h0; ((float4*)hp)[1] = h1;
        } else {
          us8 o8;
          #pragma unroll
          for(int j=0;j<8;j++){
            float vv = v[j];
            if(relu) vv = fmaxf(vv, 0.f) + 1e-6f;
            o8[j] = f2h(vv);
          }
          *(us8*)(osec + z*oStride + (long)gm2*256 + ((colTile + sc8) & 255)) = o8;
        }
      }
    }
  } else {
    #pragma unroll
    for(int mt=0;mt<MT;mt++){
      #pragma unroll
      for(int r=0;r<4;r++){
        int gm = rowTile + wr*WM + mt*16 + kq*4 + r;
        float sc = rowscale ? rowscale[z*rsStride + gm] : 1.0f;
        if(accOut){
          float* hp = accOut + z*hStride + (long)gm*256;
          if(kSplit > 1){
            #pragma unroll
            for(int nt=0;nt<NT;nt++){
              int gc = colTile + wc*WN + nt*16 + lm;
              atomicAdd(&hp[gc], acc[mt][nt][r]);
            }
          } else {
            #pragma unroll
            for(int nt=0;nt<NT;nt++){
              int gc = colTile + wc*WN + nt*16 + lm;
              hp[gc] += acc[mt][nt][r]*sc + (bias ? bias[gc] : 0.f);
            }
          }
        } else {
          #pragma unroll
          for(int nt=0;nt<NT;nt++){
            int gc = colTile + wc*WN + nt*16 + lm;
            int sec = gc >> 8;
            u16* o = (sec==0) ? o0 : ((sec==1) ? o1 : o2);
            float val = acc[mt][nt][r]*sc + (bias ? bias[gc] : 0.f);
            if((reluMask >> sec) & 1) val = fmaxf(val, 0.f) + 1e-6f;
            if(sec==0 && oLoOff){
              u16* oo = o0 + 2*z*oStride + (long)gm*256 + (gc & 255);
              u16 hb = f2h(val);
              oo[0] = hb;
              oo[oLoOff] = f2h(val - h2f(hb));
            } else {
              o[z*oStride + (long)gm*256 + (gc & 255)] = f2h(val);
            }
          }
        }
      }
    }
  }
}

// ---------------- fused out-projection: GEMM + h RMW + LN / zcalc / head ----------------
// R9 fusions (register-reuse, no sync changes):
//  - ksumIn != null (attn side): rs computed INLINE from A-registers (A IS q):
//    per-lane 64-term dot with ksum + shfl_xor(16,32) over the kq quad, then
//    epilogue takes sc via __shfl. Replaces the k_zcalc dispatch (+32MB read).
//  - headW != null (last layer): final h float4 is in registers at exactly
//    k_head's (row,lane) layout; identical reduction -> bit-identical output.
//    Replaces the k_head dispatch (+64MB read).
// R10's gather fusion REVERTED: fusedout's fragment layout (4 lanes/row x 16B)
// breaks the gather's 256B/row coalescing -> FETCH +11MB, dur 2x. Gather
// fusion requires layout-compatible consumers; keep v3 in k_spmm2.
__global__ __launch_bounds__(256) void k_fusedout(
    const u16* __restrict__ A, const u16* __restrict__ B, long bStride, long bLoOff,
    const float* __restrict__ rowscale, const float* __restrict__ ksumIn,
    const float* __restrict__ bias,
    float* __restrict__ h,
    const float* __restrict__ lnG, const float* __restrict__ lnB,
    u16* __restrict__ Lout,
    const float* __restrict__ headW, const float* __restrict__ headB,
    float* __restrict__ headOut)
{
  // smem: Bh 256x32 + Bl 256x32 u16 = 32,768B; epilogue 16x260 f32 = 16,640B
  __shared__ __align__(16) u16 smem[16384];
  u16* Bh = smem;
  u16* Bl = smem + 8192;
  float* epi = (float*)smem;

  const int t = threadIdx.x;
  const long z = blockIdx.z;
  const int rowTile = blockIdx.x*32;
  const int l = t & 63, w = t >> 6;
  const int wr = w >> 1, wc = w & 1;
  const int lm = l & 15, kq = l >> 4;
  const u16* Ab = A + z*PLANE;
  const u16* Bb = B + z*bStride;

  f32x4 acc[8];
  #pragma unroll
  for(int nt=0;nt<8;nt++) acc[nt] = (f32x4){0.f,0.f,0.f,0.f};

  // prologue: lane's A row-fragment for all 8 k-steps (64 fp16 = 32 VGPR)
  h8 areg[8];
  {
    const u16* arow = Ab + (long)(rowTile + wr*16 + lm)*256 + kq*8;
    #pragma unroll
    for(int kk=0;kk<8;kk++) areg[kk] = *(const h8*)(arow + kk*32);
  }

  // fused zcalc: rs = 1/(q . ksum + 1e-6) from A-regs (A = q). Lane holds
  // 64 of the row's 256 elems; reduce over the kq quad (lane bits 4,5).
  float rsv = 0.f;
  if(ksumIn){
    const float* kb = ksumIn + z*DD;
    float s = 0.f;
    #pragma unroll
    for(int kk=0;kk<8;kk++){
      const float4 c0v = *(const float4*)(kb + kq*8 + kk*32);
      const float4 c1v = *(const float4*)(kb + kq*8 + kk*32 + 4);
      s += (float)areg[kk][0]*c0v.x + (float)areg[kk][1]*c0v.y
         + (float)areg[kk][2]*c0v.z + (float)areg[kk][3]*c0v.w
         + (float)areg[kk][4]*c1v.x + (float)areg[kk][5]*c1v.y
         + (float)areg[kk][6]*c1v.z + (float)areg[kk][7]*c1v.w;
    }
    s += __shfl_xor(s, 16);
    s += __shfl_xor(s, 32);
    rsv = 1.0f/(s + 1e-6f);
  }

  #pragma unroll
  for(int kk=0; kk<8; ++kk){
    __syncthreads();
    #pragma unroll
    for(int li=0; li<4; li++){   // B: 256x32 tile per buffer, 4 x 16B per thread
      int f = li*256 + t;
      int row = f>>2, c = (f&3)*8;
      const u16* gp = Bb + (long)row*256 + kk*32 + c;
      ldscp(gp, &Bh[f*8]);
      ldscp(gp + bLoOff, &Bl[f*8]);
    }
    __syncthreads();
    #pragma unroll
    for(int nt=0;nt<8;nt++){
      int idx = (wc*128 + nt*16 + lm)*32 + kq*8;
      const h8 bhf = *(const h8*)&Bh[idx];
      const h8 blf = *(const h8*)&Bl[idx];
      acc[nt] = __builtin_amdgcn_mfma_f32_16x16x32_f16(areg[kk], bhf, acc[nt], 0, 0, 0);
      acc[nt] = __builtin_amdgcn_mfma_f32_16x16x32_f16(areg[kk], blf, acc[nt], 0, 0, 0);
    }
  }

  // epilogue: 2 phases of 16 rows (wave wr==p owns phase p's accumulators)
  #pragma unroll
  for(int p=0;p<2;p++){
    __syncthreads();
    if(wr == p){   // wave-uniform guard (wr constant per wave) -> shfl safe
      #pragma unroll
      for(int r=0;r<4;r++){
        int rl = kq*4 + r;
        int gm = rowTile + p*16 + rl;
        float sc;
        if(ksumIn) sc = __shfl(rsv, kq*4 + r);   // rs of row p*16+kq*4+r
        else       sc = rowscale ? rowscale[z*NN + gm] : 1.0f;
        #pragma unroll
        for(int nt=0;nt<8;nt++)
          epi[rl*260 + wc*128 + nt*16 + lm] = acc[nt][r]*sc;
      }
    }
    __syncthreads();
    // store phase: one 64-lane wave per row, float4 per lane (k_ln-identical)
    #pragma unroll
    for(int ss=0;ss<4;ss++){
      int s = ss*256 + t;
      int rl = s >> 6;               // 0..15 (uniform per wave)
      int c4 = (s & 63)*4;           // lane*4
      int gm = rowTile + p*16 + rl;
      float4 e = *(float4*)&epi[rl*260 + c4];
      float4 x;
      x.x = e.x + bias[c4+0];
      x.y = e.y + bias[c4+1];
      x.z = e.z + bias[c4+2];
      x.w = e.w + bias[c4+3];
      float* hp = h + z*PLANE + (long)gm*256 + c4;
      float4 h0 = *(float4*)hp;
      x.x += h0.x; x.y += h0.y; x.z += h0.z; x.w += h0.w;
      *(float4*)hp = x;
      if(lnG){
        float sA = x.x + x.y + x.z + x.w;
        float s2 = x.x*x.x + x.y*x.y + x.z*x.z + x.w*x.w;
        for(int o=1;o<64;o<<=1){ sA += __shfl_xor(sA,o); s2 += __shfl_xor(s2,o); }
        float m = sA*(1.0f/256.0f);
        float var = s2*(1.0f/256.0f) - m*m;
        float rr = rsqrtf(var + 1e-5f);
        const float4 gu = *(const float4*)(lnG + c4);
        const float4 bu = *(const float4*)(lnB + c4);
        ushort4 o4;
        o4.x = f2h((x.x-m)*rr*gu.x + bu.x);
        o4.y = f2h((x.y-m)*rr*gu.y + bu.y);
        o4.z = f2h((x.z-m)*rr*gu.z + bu.z);
        o4.w = f2h((x.w-m)*rr*gu.w + bu.w);
        *(ushort4*)(Lout + z*PLANE + (long)gm*256 + c4) = o4;
      } else if(headW){
        // fused head: identical reduction/code-path as the old k_head
        int d0 = c4;
        float a0 = x.x*headW[(d0+0)*3+0] + x.y*headW[(d0+1)*3+0] + x.z*headW[(d0+2)*3+0] + x.w*headW[(d0+3)*3+0];
        float a1 = x.x*headW[(d0+0)*3+1] + x.y*headW[(d0+1)*3+1] + x.z*headW[(d0+2)*3+1] + x.w*headW[(d0+3)*3+1];
        float a2 = x.x*headW[(d0+0)*3+2] + x.y*headW[(d0+1)*3+2] + x.z*headW[(d0+2)*3+2] + x.w*headW[(d0+3)*3+2];
        for(int o=1;o<64;o<<=1){
          a0 += __shfl_xor(a0,o); a1 += __shfl_xor(a1,o); a2 += __shfl_xor(a2,o);
        }
        if((t & 63)==0){
          float* op = headOut + ((long)z*NN + gm)*3;
          op[0] = a0 + headB[0];
          op[1] = a1 + headB[1];
          op[2] = a2 + headB[2];
        }
      }
    }
  }
}

// ------------- fused k+v spmm gather (fp16 planes, fp32 accum) -------------
// MODE 0: k+v gather+store, D-SPLIT via blockIdx.z (dhalf). Per-XCD-phase read
//   working set = k-half (2MB) + v-half (2MB) = 4MB = one XCD L2.
// MODE 1: z=0 -> rowdot rs = (q . gather(k))*INV6, full-D; z=1 -> v3 gather,
//   D-split by y.
template<int MODE>
__global__ __launch_bounds__(256) void k_spmm2(
    const u16* __restrict__ kin, const u16* __restrict__ vin,
    const int* __restrict__ offB, const int* __restrict__ srcB,
    u16* __restrict__ kout, u16* __restrict__ vout,
    const u16* __restrict__ q, float* __restrict__ rs){
  long z = blockIdx.x;
  const int* off = offB + z*(NN+1);
  const int* sE  = srcB + z*(long)NN*KK;

  if constexpr (MODE == 0){
    const u16* kp = kin + z*PLANE;
    const u16* vp = vin + z*PLANE;
    int row = blockIdx.y*16 + (threadIdx.x >> 4);
    int d8 = blockIdx.z*128 + (threadIdx.x & 15)*8;
    int s0 = off[row], s1 = off[row+1];
    float ak[8], av[8];
    #pragma unroll
    for(int j=0;j<8;j++){ ak[j]=0.f; av[j]=0.f; }
    int e = s0;
    for(; e+1 < s1; e += 2){
      int n0 = sE[e], n1 = sE[e+1];
      us8 k0 = *(const us8*)(kp + (long)n0*DD + d8);
      us8 k1 = *(const us8*)(kp + (long)n1*DD + d8);
      us8 v0 = *(const us8*)(vp + (long)n0*DD + d8);
      us8 v1 = *(const us8*)(vp + (long)n1*DD + d8);
      #pragma unroll
      for(int j=0;j<8;j++){
        ak[j] += h2f(k0[j]) + h2f(k1[j]);
        av[j] += h2f(v0[j]) + h2f(v1[j]);
      }
    }
    if(e < s1){
      int n0 = sE[e];
      us8 k0 = *(const us8*)(kp + (long)n0*DD + d8);
      us8 v0 = *(const us8*)(vp + (long)n0*DD + d8);
      #pragma unroll
      for(int j=0;j<8;j++){ ak[j] += h2f(k0[j]); av[j] += h2f(v0[j]); }
    }
    us8 ok, ov;
    #pragma unroll
    for(int j=0;j<8;j++){ ok[j] = f2h(ak[j]*INV6); ov[j] = f2h(av[j]*INV6); }
    *(us8*)(kout + z*PLANE + (long)row*DD + d8) = ok;
    *(us8*)(vout + z*PLANE + (long)row*DD + d8) = ov;
  } else {
    if(blockIdx.z == 0){
      const u16* kp = kin + z*PLANE;
      int row = blockIdx.y*8 + (threadIdx.x >> 5);
      int l32 = threadIdx.x & 31;
      int d8 = l32*8;
      int s0 = off[row], s1 = off[row+1];
      float ak[8];
      #pragma unroll
      for(int j=0;j<8;j++) ak[j]=0.f;
      int e = s0;
      for(; e+1 < s1; e += 2){
        int n0 = sE[e], n1 = sE[e+1];
        us8 k0 = *(const us8*)(kp + (long)n0*DD + d8);
        us8 k1 = *(const us8*)(kp + (long)n1*DD + d8);
        #pragma unroll
        for(int j=0;j<8;j++) ak[j] += h2f(k0[j]) + h2f(k1[j]);
      }
      if(e < s1){
        int n0 = sE[e];
        us8 k0 = *(const us8*)(kp + (long)n0*DD + d8);
        #pragma unroll
        for(int j=0;j<8;j++) ak[j] += h2f(k0[j]);
      }
      us8 qv = *(const us8*)(q + z*PLANE + (long)row*DD + d8);
      float s = 0.f;
      #pragma unroll
      for(int j=0;j<8;j++) s += h2f(qv[j]) * ak[j];
      for(int o=1;o<32;o<<=1) s += __shfl_xor(s,o);
      if(l32==0) rs[z*NN + row] = s*INV6;
    } else {
      const u16* vp = vin + z*PLANE;
      int row = (blockIdx.y & 511)*16 + (threadIdx.x >> 4);
      int d8 = (blockIdx.y >> 9)*128 + (threadIdx.x & 15)*8;
      int s0 = off[row], s1 = off[row+1];
      float av[8];
      #pragma unroll
      for(int j=0;j<8;j++) av[j]=0.f;
      int e = s0;
      for(; e+1 < s1; e += 2){
        int n0 = sE[e], n1 = sE[e+1];
        us8 v0 = *(const us8*)(vp + (long)n0*DD + d8);
        us8 v1 = *(const us8*)(vp + (long)n1*DD + d8);
        #pragma unroll
        for(int j=0;j<8;j++) av[j] += h2f(v0[j]) + h2f(v1[j]);
      }
      if(e < s1){
        int n0 = sE[e];
        us8 v0 = *(const us8*)(vp + (long)n0*DD + d8);
        #pragma unroll
        for(int j=0;j<8;j++) av[j] += h2f(v0[j]);
      }
      us8 ov;
      #pragma unroll
      for(int j=0;j<8;j++) ov[j] = f2h(av[j]*INV6);
      *(us8*)(vout + z*PLANE + (long)row*DD + d8) = ov;
    }
  }
}

// ---- dual transpose fp16 [8192][256] -> [256][8192] + fused ksum ----
// R9: k tensor (even zz) also accumulates ksum[d] = sum_n k[n][d] from the
// transpose-read registers: 16-elem per-thread partial, quad shuffle-reduce,
// one atomicAdd per 64-row column partial (device-scope). Replaces k_ksum.
__global__ __launch_bounds__(256) void k_transp2(
    const u16* __restrict__ in0, u16* __restrict__ out0,
    const u16* __restrict__ in1, u16* __restrict__ out1,
    float* __restrict__ ksum){
  __shared__ u16 tile[64][72];
  int zz = blockIdx.z;
  long z = zz >> 1;
  const u16* ip = ((zz & 1) ? in1 : in0) + z*PLANE;
  u16* op = ((zz & 1) ? out1 : out0) + z*PLANE;
  int r0 = blockIdx.x*64, c0 = blockIdx.y*64;
  int t = threadIdx.x;
  {
    int r = t>>2, cg = (t&3)*16;
    *(us8*)&tile[r][cg]   = *(const us8*)(ip + (long)(r0+r)*DD + c0 + cg);
    *(us8*)&tile[r][cg+8] = *(const us8*)(ip + (long)(r0+r)*DD + c0 + cg + 8);
  }
  __syncthreads();
  {
    int c = t>>2, rg = t&3;
    us8 a, b;
    #pragma unroll
    for(int j=0;j<8;j++){ a[j] = tile[rg*16+j][c]; b[j] = tile[rg*16+8+j][c]; }
    u16* dst = op + (long)(c0+c)*NN + r0 + rg*16;
    *(us8*)dst = a; *(us8*)(dst+8) = b;
    if((zz & 1)==0){
      float p = 0.f;
      #pragma unroll
      for(int j=0;j<8;j++) p += h2f(a[j]) + h2f(b[j]);
      p += __shfl_xor(p, 1);
      p += __shfl_xor(p, 2);
      if(rg == 0) atomicAdd(&ksum[z*DD + c0 + c], p);
    }
  }
}

struct Carve {
  float *h; u16 *L,*Q,*Bp,*Cp,*T;
  float *kvf; u16 *w2t;
  float *ksum,*rs;
  int *off,*cursor,*srcE;
  u16 *wt_gqkv,*wt_aqkv,*wt_gout,*wt_aout;
  size_t total;
};

static Carve carve(char* base, int C){
  Carve c;
  size_t cur = 0;
  auto bump = [&](size_t bytes)->char*{
    char* p = base ? base + cur : (char*)0;
    cur += (bytes + 255) & ~(size_t)255;
    return p;
  };
  c.h    = (float*)bump((size_t)C*PLANE*4);
  c.L    = (u16*)bump((size_t)C*PLANE*2);   // LN out / hop pong / kT
  c.Q    = (u16*)bump((size_t)C*PLANE*2);
  c.Bp   = (u16*)bump((size_t)C*PLANE*2);   // k
  c.Cp   = (u16*)bump((size_t)C*PLANE*2);   // v
  c.T    = (u16*)bump((size_t)C*PLANE*2);   // v-hop pong / v3 / vT
  c.kvf  = (float*)bump((size_t)C*DD*DD*4);
  c.w2t  = (u16*)bump((size_t)C*2*DD*DD*2); // split pair
  c.ksum = (float*)bump((size_t)C*DD*4);
  c.rs   = (float*)bump((size_t)C*NN*4);
  c.off  = (int*)bump((size_t)BB*(NN+1)*4);
  c.cursor=(int*)bump((size_t)BB*(NN+1)*4);
  c.srcE = (int*)bump((size_t)NE*4);
  c.wt_gqkv = (u16*)bump((size_t)LL*2*768*256*2);
  c.wt_aqkv = (u16*)bump((size_t)LL*2*768*256*2);
  c.wt_gout = (u16*)bump((size_t)LL*2*256*256*2);
  c.wt_aout = (u16*)bump((size_t)LL*2*256*256*2);
  c.total = cur;
  return c;
}

extern "C" void kernel_launch(void* const* d_in, const int* in_sizes, int n_in,
                              void* d_out, int out_size, void* d_ws, size_t ws_size,
                              hipStream_t stream)
{
  const float* x        = (const float*)d_in[0];
  const int*   knn      = (const int*)d_in[1];
  const float* emb_w    = (const float*)d_in[2];
  const float* emb_b    = (const float*)d_in[3];
  const float* norm_g   = (const float*)d_in[4];
  const float* norm_b   = (const float*)d_in[5];
  const float* grf_qkv  = (const float*)d_in[6];
  const float* grf_outw = (const float*)d_in[7];
  const float* grf_outb = (const float*)d_in[8];
  const float* attn_qkv = (const float*)d_in[9];
  const float* attn_outw= (const float*)d_in[10];
  const float* attn_outb= (const float*)d_in[11];
  const float* head_w   = (const float*)d_in[12];
  const float* head_b   = (const float*)d_in[13];
  float* out = (float*)d_out;

  int C = 1;
  for(int cc=BB; cc>=1; cc>>=1){ if(carve(nullptr, cc).total <= ws_size){ C = cc; break; } }
  Carve ws = carve((char*)d_ws, C);

  // ---- weight prep (hi/lo fp16, transposed to [N][K]) ----
  k_prepw<<<dim3(768, LL), 256, 0, stream>>>(grf_qkv,  ws.wt_gqkv, 768);
  k_prepw<<<dim3(768, LL), 256, 0, stream>>>(attn_qkv, ws.wt_aqkv, 768);
  k_prepw<<<dim3(256, LL), 256, 0, stream>>>(grf_outw, ws.wt_gout, 256);
  k_prepw<<<dim3(256, LL), 256, 0, stream>>>(attn_outw,ws.wt_aout, 256);

  // ---- CSR build for all batches ----
  hipMemsetAsync(ws.off, 0, (size_t)BB*(NN+1)*sizeof(int), stream);
  k_count<<<dim3((NE+255)/256), 256, 0, stream>>>(knn, ws.off);
  k_scan<<<dim3(BB), 1024, 0, stream>>>(ws.off);
  hipMemcpyAsync(ws.cursor, ws.off, (size_t)BB*(NN+1)*sizeof(int), hipMemcpyDeviceToDevice, stream);
  k_fill<<<dim3((NE+255)/256), 256, 0, stream>>>(knn, ws.cursor, ws.srcE);

  const long PL = PLANE;
  for(int b0=0; b0<BB; b0+=C){
    const int* offB  = ws.off  + (long)b0*(NN+1);
    const int* srcB  = ws.srcE + (long)b0*NN*KK;

    k_embed<<<dim3(NN, C), 256, 0, stream>>>(x + (long)b0*NN*3, emb_w, emb_b, ws.h);
    k_ln<<<dim3(NN/4, C), 256, 0, stream>>>(ws.h, norm_g, norm_b, ws.L);

    for(int i=0; i<LL; i++){
      // ===== GRF sublayer =====
      k_mgemm<128,128,false,false,true><<<dim3(64, 6, C), 256, 0, stream>>>(
          ws.L, PL, 0, 256, 1,
          ws.wt_gqkv + (long)i*2*768*256, 0, (long)768*256,
          nullptr, 0, nullptr,
          ws.Q, ws.Bp, ws.Cp, PL, 0, 0, nullptr, 0);
      k_spmm2<0><<<dim3(C, NN/16, 2), 256, 0, stream>>>(ws.Bp, ws.Cp, offB, srcB, ws.L, ws.T, nullptr, nullptr);
      k_spmm2<0><<<dim3(C, NN/16, 2), 256, 0, stream>>>(ws.L,  ws.T,  offB, srcB, ws.Bp, ws.Cp, nullptr, nullptr);
      k_spmm2<1><<<dim3(C, NN/8, 2), 256, 0, stream>>>(ws.Bp, ws.Cp, offB, srcB, nullptr, ws.T, ws.Q, ws.rs);
      // h += (rs*v3) @ grf_outw + grf_outb ; fused LN -> L (attn LN, norm 2i+1)
      k_fusedout<<<dim3(NN/32, 1, C), 256, 0, stream>>>(
          ws.T, ws.wt_gout + (long)i*2*256*256, 0, (long)256*256,
          ws.rs, nullptr, grf_outb + (long)i*DD, ws.h,
          norm_g + (2*i+1)*DD, norm_b + (2*i+1)*DD, ws.L,
          nullptr, nullptr, nullptr);

      // ===== linear attention sublayer =====
      k_mgemm<128,128,false,false,true><<<dim3(64, 6, C), 256, 0, stream>>>(
          ws.L, PL, 0, 256, 1,
          ws.wt_aqkv + (long)i*2*768*256, 0, (long)768*256,
          nullptr, 0, nullptr,
          ws.Q, ws.Bp, ws.Cp, PL, 3 /* relu+1e-6 on q,k */, 0, nullptr, 0);
      // kT = Bp^T -> L ; vT = Cp^T -> T ; ksum fused (atomics)
      hipMemsetAsync(ws.ksum, 0, (size_t)C*DD*sizeof(float), stream);
      k_transp2<<<dim3(NN/64, DD/64, 2*C), 256, 0, stream>>>(ws.Bp, ws.L, ws.Cp, ws.T, ws.ksum);
      // kv[d][e] = sum_n kT[d][n] * vT[e][n]  (split-K=8, atomic fp32)
      hipMemsetAsync(ws.kvf, 0, (size_t)C*DD*DD*sizeof(float), stream);
      k_mgemm<64,64,false,false,false><<<dim3(4, 4, C*8), 256, 0, stream>>>(
          ws.L, PL, 0, NN, 8,
          ws.T, PL, 0,
          nullptr, 0, nullptr,
          nullptr, nullptr, nullptr, 0, 0, 0, ws.kvf, (long)DD*DD);
      // w2t[n][d] = sum_e WoutT[n][e](split) * kv[d][e]  -> split fp16 pair
      k_mgemm<64,64,true,true,false><<<dim3(4, 4, C), 256, 0, stream>>>(
          ws.wt_aout + (long)i*2*256*256, 0, (long)256*256, 256, 1,
          ws.kvf, (long)DD*DD, 0,
          nullptr, 0, nullptr,
          ws.w2t, nullptr, nullptr, (long)DD*DD, 0, (long)DD*DD,
          nullptr, 0);
      // h += (z*q) @ w2 + attn_outb ; rs inline from ksum; fused LN -> L,
      // or (last layer) fused head -> out
      const float* g2 = (i==LL-1) ? nullptr : norm_g + (2*i+2)*DD;
      const float* b2 = (i==LL-1) ? nullptr : norm_b + (2*i+2)*DD;
      k_fusedout<<<dim3(NN/32, 1, C), 256, 0, stream>>>(
          ws.Q, ws.w2t, 2L*DD*DD, (long)DD*DD,
          nullptr, ws.ksum, attn_outb + (long)i*DD, ws.h,
          g2, b2, ws.L,
          (i==LL-1) ? head_w : nullptr,
          (i==LL-1) ? head_b : nullptr,
          (i==LL-1) ? (out + (long)b0*NN*3) : nullptr);
    }
  }
}

// Round 12
// 2342.392 us; speedup vs baseline: 1.1752x; 1.0483x over previous
//
#include <hip/hip_runtime.h>

#define BB 8
#define NN 8192
#define KK 6
#define DD 256
#define LL 5
#define NE (BB*NN*KK)       // 393216
#define PLANE (NN*DD)       // 2097152 elems per batch
#define INV6 (1.0f/6.000001f)

typedef unsigned short u16;
typedef __attribute__((ext_vector_type(8))) _Float16 h8;
typedef __attribute__((ext_vector_type(8))) unsigned short us8;
typedef __attribute__((ext_vector_type(4))) float f32x4;

__device__ __forceinline__ u16 f2h(float f){
  union { _Float16 h; u16 u; } c; c.h = (_Float16)f; return c.u;
}
__device__ __forceinline__ float h2f(u16 u){
  union { _Float16 h; u16 u; } c; c.u = u; return (float)c.h;
}

// async global->LDS 16B copy: LDS dest must be wave-uniform base + lane*16
__device__ __forceinline__ void ldscp(const u16* g, u16* l){
  __builtin_amdgcn_global_load_lds(
      (const __attribute__((address_space(1))) void*)g,
      (__attribute__((address_space(3))) void*)l, 16, 0, 0);
}

// ---------------- CSR build ----------------
__global__ void k_count(const int* __restrict__ knn, int* __restrict__ off){
  int e = blockIdx.x*256 + threadIdx.x;
  if(e >= NE) return;
  int b = e / (NN*KK);
  int j = knn[e];
  atomicAdd(&off[b*(NN+1) + 1 + j], 1);
}

__global__ __launch_bounds__(1024) void k_scan(int* __restrict__ offAll){
  __shared__ int lds[1024];
  __shared__ int carry_s;
  int* off = offAll + blockIdx.x*(NN+1);
  const int len = NN+1;
  int t = threadIdx.x;
  if(t==0) carry_s = 0;
  __syncthreads();
  for(int base=0; base<len; base+=1024){
    int x = (base+t < len) ? off[base+t] : 0;
    lds[t] = x; __syncthreads();
    for(int s=1; s<1024; s<<=1){
      int v = (t>=s) ? lds[t-s] : 0;
      __syncthreads();
      lds[t] += v;
      __syncthreads();
    }
    int incl = lds[t];
    int carry = carry_s;
    __syncthreads();
    if(base+t < len) off[base+t] = incl + carry;
    if(t==1023) carry_s = carry + incl;
    __syncthreads();
  }
}

__global__ void k_fill(const int* __restrict__ knn, int* __restrict__ cursor, int* __restrict__ srcE){
  int e = blockIdx.x*256 + threadIdx.x;
  if(e >= NE) return;
  int b = e / (NN*KK);
  int n = (e % (NN*KK)) / KK;
  int j = knn[e];
  int pos = atomicAdd(&cursor[b*(NN+1) + j], 1);
  srcE[(long)b*NN*KK + pos] = n;
}

// ---- weight prep: W fp32 [L][256][N] -> Wt hi/lo fp16 [L][2][N][256] ----
__global__ __launch_bounds__(256) void k_prepw(const float* __restrict__ W, u16* __restrict__ Wt, int N){
  int n = blockIdx.x, l = blockIdx.y, k = threadIdx.x;
  float x = W[((long)l*256 + k)*N + n];
  u16 hb = f2h(x);
  Wt[(((long)l*2 + 0)*N + n)*256 + k] = hb;
  Wt[(((long)l*2 + 1)*N + n)*256 + k] = f2h(x - h2f(hb));
}

// ---------------- embed ----------------
__global__ __launch_bounds__(256) void k_embed(const float* __restrict__ x, const float* __restrict__ ew,
                        const float* __restrict__ eb, float* __restrict__ h){
  int g = blockIdx.x, z = blockIdx.y, d = threadIdx.x;
  const float* xp = x + ((long)z*NN + g)*3;
  h[(long)z*PLANE + (long)g*DD + d] = xp[0]*ew[0*DD+d] + xp[1]*ew[1*DD+d] + xp[2]*ew[2*DD+d] + eb[d];
}

// ---------------- layernorm fp32 -> fp16 single plane (layer-0 only) ----------------
__global__ __launch_bounds__(256) void k_ln(const float* __restrict__ h, const float* __restrict__ g,
                     const float* __restrict__ bia, u16* __restrict__ out){
  long z = blockIdx.y;
  int row = blockIdx.x*4 + (threadIdx.x >> 6);
  int lane = threadIdx.x & 63;
  const float4 x = *(const float4*)(h + z*PLANE + (long)row*DD + lane*4);
  float s  = x.x + x.y + x.z + x.w;
  float s2 = x.x*x.x + x.y*x.y + x.z*x.z + x.w*x.w;
  for(int o=1;o<64;o<<=1){ s += __shfl_xor(s,o); s2 += __shfl_xor(s2,o); }
  float m = s*(1.0f/256.0f);
  float var = s2*(1.0f/256.0f) - m*m;
  float r = rsqrtf(var + 1e-5f);
  const float4 gu = *(const float4*)(g + lane*4);
  const float4 bu = *(const float4*)(bia + lane*4);
  ushort4 o4;
  o4.x = f2h((x.x-m)*r*gu.x + bu.x);
  o4.y = f2h((x.y-m)*r*gu.y + bu.y);
  o4.z = f2h((x.z-m)*r*gu.z + bu.z);
  o4.w = f2h((x.w-m)*r*gu.w + bu.w);
  *(ushort4*)(out + z*PLANE + (long)row*DD + lane*4) = o4;
}

// ---------------- fp16 MFMA GEMM ----------------
// R8-validated dbuf stage-early/drain-late K-loop for !BF32.
// R12: transposed-output mode for the attn qkv call (o1T!=null, sec>=1):
// k/v sections are stored DIRECTLY TRANSPOSED from acc (lane's 4 r-values are
// 4 consecutive rows at fixed col -> one ushort4 = 8B run of kT[col][*]),
// no LDS epi, no barriers; ksum[col] accumulated from the f2h-rounded values
// (same rounded values transp2's fused ksum summed; fp32 order differs only).
// This deletes k_transp2 + the dead row-major k/v planes. Values bit-identical.
template<int BM,int BN,bool ASPLIT,bool BF32,bool BSPLIT>
__global__ __launch_bounds__(256) void k_mgemm(
    const u16* __restrict__ A, long aStride, long aLoOff, int K, int kSplit,
    const void* __restrict__ Bv, long bStride, long bLoOff,
    const float* __restrict__ rowscale, long rsStride,
    const float* __restrict__ bias,
    u16* __restrict__ o0, u16* __restrict__ o1, u16* __restrict__ o2,
    long oStride, int reluMask, long oLoOff,
    float* __restrict__ accOut, long hStride,
    u16* __restrict__ o1T, u16* __restrict__ o2T, float* __restrict__ ksumOut)
{
  constexpr int WM = BM/2, WN = BN/2, MT = WM/16, NT = WN/16;
  constexpr int STG1 = BM*32*(ASPLIT?2:1) + BN*32*(BSPLIT?2:1);
  constexpr int STGT = BF32 ? STG1 : 2*STG1;      // dbuf for !BF32
  constexpr int EPI = (BM==128) ? 32*132*2 : 0;
  constexpr int SM  = (STGT > EPI) ? STGT : EPI;
  __shared__ __align__(16) u16 smem[SM];
  float* epi = (float*)smem;

  const int t = threadIdx.x;
  const int nz = blockIdx.z;
  const long z = nz / kSplit;
  const int chunk = nz % kSplit;
  const int kLen = K / kSplit, kLo = chunk * kLen;
  const int rowTile = blockIdx.x*BM, colTile = blockIdx.y*BN;
  const int l = t & 63, w = t >> 6;
  const int wr = w >> 1, wc = w & 1;
  const int lm = l & 15, kq = l >> 4;

  f32x4 acc[MT][NT];
  #pragma unroll
  for(int mt=0;mt<MT;mt++)
    #pragma unroll
    for(int nt=0;nt<NT;nt++) acc[mt][nt] = (f32x4){0.f,0.f,0.f,0.f};

  if constexpr (!BF32){
    // ---- double-buffered pipelined K-loop (stage-early, drain-late) ----
    auto stageAB = [&](int buf, int k0){
      u16* Ahi_ = smem + (size_t)buf*STG1;
      u16* Alo_ = Ahi_ + BM*32;
      u16* Bhi_ = Ahi_ + BM*32*(ASPLIT?2:1);
      u16* Blo_ = Bhi_ + BN*32;
      {
        constexpr int NCH = BM/64;
        #pragma unroll
        for(int li=0; li<NCH; li++){
          int f = li*256 + t;
          int row = f>>2, c = (f&3)*8;
          const u16* gp = A + z*aStride + (long)(rowTile+row)*K + k0 + c;
          ldscp(gp, &Ahi_[f*8]);
          if constexpr (ASPLIT) ldscp(gp + aLoOff, &Alo_[f*8]);
        }
      }
      {
        constexpr int NCH = BN/64;
        #pragma unroll
        for(int li=0; li<NCH; li++){
          int f = li*256 + t;
          int row = f>>2, c = (f&3)*8;
          const u16* gp = (const u16*)Bv + z*bStride + (long)(colTile+row)*K + k0 + c;
          ldscp(gp, &Bhi_[f*8]);
          if constexpr (BSPLIT) ldscp(gp + bLoOff, &Blo_[f*8]);
        }
      }
    };

    const int nsteps = kLen >> 5;
    stageAB(0, kLo);
    __syncthreads();                 // drain initial stage
    int cur = 0;
    for(int ks=0; ks<nsteps; ++ks){
      if(ks+1 < nsteps) stageAB(cur^1, kLo + ((ks+1)<<5));   // prefetch next
      const u16* Ahi_ = smem + (size_t)cur*STG1;
      const u16* Alo_ = Ahi_ + BM*32;
      const u16* Bhi_ = Ahi_ + BM*32*(ASPLIT?2:1);
      const u16* Blo_ = Bhi_ + BN*32;
      h8 ah[MT], al[MT], bh[NT], bl[NT];
      #pragma unroll
      for(int mt=0;mt<MT;mt++){
        int idx = (wr*WM + mt*16 + lm)*32 + kq*8;
        ah[mt] = *(const h8*)&Ahi_[idx];
        if constexpr (ASPLIT) al[mt] = *(const h8*)&Alo_[idx];
      }
      #pragma unroll
      for(int nt=0;nt<NT;nt++){
        int idx = (wc*WN + nt*16 + lm)*32 + kq*8;
        bh[nt] = *(const h8*)&Bhi_[idx];
        if constexpr (BSPLIT) bl[nt] = *(const h8*)&Blo_[idx];
      }
      #pragma unroll
      for(int mt=0;mt<MT;mt++)
        #pragma unroll
        for(int nt=0;nt<NT;nt++){
          acc[mt][nt] = __builtin_amdgcn_mfma_f32_16x16x32_f16(ah[mt], bh[nt], acc[mt][nt], 0, 0, 0);
          if constexpr (BSPLIT)
            acc[mt][nt] = __builtin_amdgcn_mfma_f32_16x16x32_f16(ah[mt], bl[nt], acc[mt][nt], 0, 0, 0);
          if constexpr (ASPLIT)
            acc[mt][nt] = __builtin_amdgcn_mfma_f32_16x16x32_f16(al[mt], bh[nt], acc[mt][nt], 0, 0, 0);
        }
      __syncthreads();               // single full drain per step, after MFMA
      cur ^= 1;
    }
  } else {
    // ---- legacy single-buffer loop (BF32/w2t path) ----
    u16* Ahi = smem;
    u16* Alo = smem + BM*32;
    u16* Bhi = smem + BM*32*(ASPLIT?2:1);
    for(int k0=kLo; k0<kLo+kLen; k0+=32){
      __syncthreads();
      {
        constexpr int NCH = BM/64;
        #pragma unroll
        for(int li=0; li<NCH; li++){
          int f = li*256 + t;
          int row = f>>2, c = (f&3)*8;
          const u16* gp = A + z*aStride + (long)(rowTile+row)*K + k0 + c;
          ldscp(gp, &Ahi[f*8]);
          if constexpr (ASPLIT) ldscp(gp + aLoOff, &Alo[f*8]);
        }
      }
      {
        constexpr int NCH = BN/64;
        #pragma unroll
        for(int li=0; li<NCH; li++){
          int f = li*256 + t;
          int row = f>>2, c = (f&3)*8;
          const float* src = (const float*)Bv + z*bStride + (long)(colTile+row)*K + k0 + c;
          float4 v0 = ((const float4*)src)[0], v1 = ((const float4*)src)[1];
          us8 hv;
          hv[0]=f2h(v0.x); hv[1]=f2h(v0.y); hv[2]=f2h(v0.z); hv[3]=f2h(v0.w);
          hv[4]=f2h(v1.x); hv[5]=f2h(v1.y); hv[6]=f2h(v1.z); hv[7]=f2h(v1.w);
          *(us8*)&Bhi[f*8] = hv;
        }
      }
      __syncthreads();
      h8 ah[MT], al[MT], bh[NT];
      #pragma unroll
      for(int mt=0;mt<MT;mt++){
        int idx = (wr*WM + mt*16 + lm)*32 + kq*8;
        ah[mt] = *(const h8*)&Ahi[idx];
        if constexpr (ASPLIT) al[mt] = *(const h8*)&Alo[idx];
      }
      #pragma unroll
      for(int nt=0;nt<NT;nt++){
        int idx = (wc*WN + nt*16 + lm)*32 + kq*8;
        bh[nt] = *(const h8*)&Bhi[idx];
      }
      #pragma unroll
      for(int mt=0;mt<MT;mt++)
        #pragma unroll
        for(int nt=0;nt<NT;nt++){
          acc[mt][nt] = __builtin_amdgcn_mfma_f32_16x16x32_f16(ah[mt], bh[nt], acc[mt][nt], 0, 0, 0);
          if constexpr (ASPLIT)
            acc[mt][nt] = __builtin_amdgcn_mfma_f32_16x16x32_f16(al[mt], bh[nt], acc[mt][nt], 0, 0, 0);
        }
    }
  }

  if constexpr (BM == 128){
    const int sec = colTile >> 8;
    if(o1T && sec >= 1){
      // ---- R12 transposed store path (k/v sections of attn qkv) ----
      // lane's acc[mt][nt][r] covers rows rowTile+wr*64+mt*16+kq*4+r at fixed
      // col -> ushort4 = 4 consecutive rows of oT[col][*]. Block-uniform
      // branch (sec from colTile) -> no barrier divergence (none used here).
      u16* oT = (sec==1) ? o1T : o2T;
      const bool relu = (reluMask >> sec) & 1;
      float kpart[NT];
      #pragma unroll
      for(int nt=0;nt<NT;nt++) kpart[nt] = 0.f;
      #pragma unroll
      for(int mt=0;mt<MT;mt++){
        #pragma unroll
        for(int nt=0;nt<NT;nt++){
          int gcs = (colTile & 255) + wc*WN + nt*16 + lm;
          int gmb = rowTile + wr*WM + mt*16 + kq*4;
          ushort4 o4;
          #pragma unroll
          for(int r=0;r<4;r++){
            float val = acc[mt][nt][r];
            if(relu) val = fmaxf(val, 0.f) + 1e-6f;
            u16 hv = f2h(val);
            ((u16*)&o4)[r] = hv;
            if(sec==1) kpart[nt] += h2f(hv);
          }
          *(ushort4*)(oT + z*oStride + (long)gcs*NN + gmb) = o4;
        }
      }
      if(sec==1 && ksumOut){
        #pragma unroll
        for(int nt=0;nt<NT;nt++){
          float p = kpart[nt];
          p += __shfl_xor(p, 16);
          p += __shfl_xor(p, 32);
          if(kq==0){
            int gcs = (colTile & 255) + wc*WN + nt*16 + lm;
            atomicAdd(&ksumOut[z*DD + gcs], p);
          }
        }
      }
    } else {
    u16* osec = (sec==0) ? o0 : ((sec==1) ? o1 : o2);
    const bool relu = (reluMask >> sec) & 1;
    #pragma unroll
    for(int mt=0;mt<MT;mt++){
      __syncthreads();
      #pragma unroll
      for(int r=0;r<4;r++){
        int gm = rowTile + wr*64 + mt*16 + kq*4 + r;
        float sc = rowscale ? rowscale[z*rsStride + gm] : 1.0f;
        int rl = wr*16 + kq*4 + r;
        #pragma unroll
        for(int nt=0;nt<NT;nt++)
          epi[rl*132 + wc*64 + nt*16 + lm] = acc[mt][nt][r]*sc;
      }
      __syncthreads();
      #pragma unroll
      for(int ss=0;ss<2;ss++){
        int s = ss*256 + t;
        int rl = s >> 4, sc8 = (s & 15)*8;
        int gm2 = rowTile + (rl>>4)*64 + mt*16 + (rl & 15);
        float v[8];
        #pragma unroll
        for(int j=0;j<8;j++) v[j] = epi[rl*132 + sc8 + j];
        if(bias){
          const float* bp = bias + colTile + sc8;
          #pragma unroll
          for(int j=0;j<8;j++) v[j] += bp[j];
        }
        if(accOut){
          float* hp = accOut + z*hStride + (long)gm2*256 + colTile + sc8;
          float4 h0 = ((float4*)hp)[0], h1 = ((float4*)hp)[1];
          h0.x += v[0]; h0.y += v[1]; h0.z += v[2]; h0.w += v[3];
          h1.x += v[4]; h1.y += v[5]; h1.z += v[6]; h1.w += v[7];
          ((float4*)hp)[0] = h0; ((float4*)hp)[1] = h1;
        } else {
          us8 o8;
          #pragma unroll
          for(int j=0;j<8;j++){
            float vv = v[j];
            if(relu) vv = fmaxf(vv, 0.f) + 1e-6f;
            o8[j] = f2h(vv);
          }
          *(us8*)(osec + z*oStride + (long)gm2*256 + ((colTile + sc8) & 255)) = o8;
        }
      }
    }
    }
  } else {
    #pragma unroll
    for(int mt=0;mt<MT;mt++){
      #pragma unroll
      for(int r=0;r<4;r++){
        int gm = rowTile + wr*WM + mt*16 + kq*4 + r;
        float sc = rowscale ? rowscale[z*rsStride + gm] : 1.0f;
        if(accOut){
          float* hp = accOut + z*hStride + (long)gm*256;
          if(kSplit > 1){
            #pragma unroll
            for(int nt=0;nt<NT;nt++){
              int gc = colTile + wc*WN + nt*16 + lm;
              atomicAdd(&hp[gc], acc[mt][nt][r]);
            }
          } else {
            #pragma unroll
            for(int nt=0;nt<NT;nt++){
              int gc = colTile + wc*WN + nt*16 + lm;
              hp[gc] += acc[mt][nt][r]*sc + (bias ? bias[gc] : 0.f);
            }
          }
        } else {
          #pragma unroll
          for(int nt=0;nt<NT;nt++){
            int gc = colTile + wc*WN + nt*16 + lm;
            int sec = gc >> 8;
            u16* o = (sec==0) ? o0 : ((sec==1) ? o1 : o2);
            float val = acc[mt][nt][r]*sc + (bias ? bias[gc] : 0.f);
            if((reluMask >> sec) & 1) val = fmaxf(val, 0.f) + 1e-6f;
            if(sec==0 && oLoOff){
              u16* oo = o0 + 2*z*oStride + (long)gm*256 + (gc & 255);
              u16 hb = f2h(val);
              oo[0] = hb;
              oo[oLoOff] = f2h(val - h2f(hb));
            } else {
              o[z*oStride + (long)gm*256 + (gc & 255)] = f2h(val);
            }
          }
        }
      }
    }
  }
}

// ---------------- fused out-projection: GEMM + h RMW + LN / zcalc / head ----------------
// R9 fusions (register-reuse, no sync changes):
//  - ksumIn != null (attn side): rs computed INLINE from A-registers (A IS q).
//  - headW != null (last layer): fused head, bit-identical to old k_head.
// R10's gather fusion stays REVERTED (layout-incompatible, FETCH +11MB, 2x dur).
__global__ __launch_bounds__(256) void k_fusedout(
    const u16* __restrict__ A, const u16* __restrict__ B, long bStride, long bLoOff,
    const float* __restrict__ rowscale, const float* __restrict__ ksumIn,
    const float* __restrict__ bias,
    float* __restrict__ h,
    const float* __restrict__ lnG, const float* __restrict__ lnB,
    u16* __restrict__ Lout,
    const float* __restrict__ headW, const float* __restrict__ headB,
    float* __restrict__ headOut)
{
  // smem: Bh 256x32 + Bl 256x32 u16 = 32,768B; epilogue 16x260 f32 = 16,640B
  __shared__ __align__(16) u16 smem[16384];
  u16* Bh = smem;
  u16* Bl = smem + 8192;
  float* epi = (float*)smem;

  const int t = threadIdx.x;
  const long z = blockIdx.z;
  const int rowTile = blockIdx.x*32;
  const int l = t & 63, w = t >> 6;
  const int wr = w >> 1, wc = w & 1;
  const int lm = l & 15, kq = l >> 4;
  const u16* Ab = A + z*PLANE;
  const u16* Bb = B + z*bStride;

  f32x4 acc[8];
  #pragma unroll
  for(int nt=0;nt<8;nt++) acc[nt] = (f32x4){0.f,0.f,0.f,0.f};

  // prologue: lane's A row-fragment for all 8 k-steps (64 fp16 = 32 VGPR)
  h8 areg[8];
  {
    const u16* arow = Ab + (long)(rowTile + wr*16 + lm)*256 + kq*8;
    #pragma unroll
    for(int kk=0;kk<8;kk++) areg[kk] = *(const h8*)(arow + kk*32);
  }

  // fused zcalc: rs = 1/(q . ksum + 1e-6) from A-regs (A = q). Lane holds
  // 64 of the row's 256 elems; reduce over the kq quad (lane bits 4,5).
  float rsv = 0.f;
  if(ksumIn){
    const float* kb = ksumIn + z*DD;
    float s = 0.f;
    #pragma unroll
    for(int kk=0;kk<8;kk++){
      const float4 c0v = *(const float4*)(kb + kq*8 + kk*32);
      const float4 c1v = *(const float4*)(kb + kq*8 + kk*32 + 4);
      s += (float)areg[kk][0]*c0v.x + (float)areg[kk][1]*c0v.y
         + (float)areg[kk][2]*c0v.z + (float)areg[kk][3]*c0v.w
         + (float)areg[kk][4]*c1v.x + (float)areg[kk][5]*c1v.y
         + (float)areg[kk][6]*c1v.z + (float)areg[kk][7]*c1v.w;
    }
    s += __shfl_xor(s, 16);
    s += __shfl_xor(s, 32);
    rsv = 1.0f/(s + 1e-6f);
  }

  #pragma unroll
  for(int kk=0; kk<8; ++kk){
    __syncthreads();
    #pragma unroll
    for(int li=0; li<4; li++){   // B: 256x32 tile per buffer, 4 x 16B per thread
      int f = li*256 + t;
      int row = f>>2, c = (f&3)*8;
      const u16* gp = Bb + (long)row*256 + kk*32 + c;
      ldscp(gp, &Bh[f*8]);
      ldscp(gp + bLoOff, &Bl[f*8]);
    }
    __syncthreads();
    #pragma unroll
    for(int nt=0;nt<8;nt++){
      int idx = (wc*128 + nt*16 + lm)*32 + kq*8;
      const h8 bhf = *(const h8*)&Bh[idx];
      const h8 blf = *(const h8*)&Bl[idx];
      acc[nt] = __builtin_amdgcn_mfma_f32_16x16x32_f16(areg[kk], bhf, acc[nt], 0, 0, 0);
      acc[nt] = __builtin_amdgcn_mfma_f32_16x16x32_f16(areg[kk], blf, acc[nt], 0, 0, 0);
    }
  }

  // epilogue: 2 phases of 16 rows (wave wr==p owns phase p's accumulators)
  #pragma unroll
  for(int p=0;p<2;p++){
    __syncthreads();
    if(wr == p){   // wave-uniform guard (wr constant per wave) -> shfl safe
      #pragma unroll
      for(int r=0;r<4;r++){
        int rl = kq*4 + r;
        int gm = rowTile + p*16 + rl;
        float sc;
        if(ksumIn) sc = __shfl(rsv, kq*4 + r);   // rs of row p*16+kq*4+r
        else       sc = rowscale ? rowscale[z*NN + gm] : 1.0f;
        #pragma unroll
        for(int nt=0;nt<8;nt++)
          epi[rl*260 + wc*128 + nt*16 + lm] = acc[nt][r]*sc;
      }
    }
    __syncthreads();
    // store phase: one 64-lane wave per row, float4 per lane (k_ln-identical)
    #pragma unroll
    for(int ss=0;ss<4;ss++){
      int s = ss*256 + t;
      int rl = s >> 6;               // 0..15 (uniform per wave)
      int c4 = (s & 63)*4;           // lane*4
      int gm = rowTile + p*16 + rl;
      float4 e = *(float4*)&epi[rl*260 + c4];
      float4 x;
      x.x = e.x + bias[c4+0];
      x.y = e.y + bias[c4+1];
      x.z = e.z + bias[c4+2];
      x.w = e.w + bias[c4+3];
      float* hp = h + z*PLANE + (long)gm*256 + c4;
      float4 h0 = *(float4*)hp;
      x.x += h0.x; x.y += h0.y; x.z += h0.z; x.w += h0.w;
      *(float4*)hp = x;
      if(lnG){
        float sA = x.x + x.y + x.z + x.w;
        float s2 = x.x*x.x + x.y*x.y + x.z*x.z + x.w*x.w;
        for(int o=1;o<64;o<<=1){ sA += __shfl_xor(sA,o); s2 += __shfl_xor(s2,o); }
        float m = sA*(1.0f/256.0f);
        float var = s2*(1.0f/256.0f) - m*m;
        float rr = rsqrtf(var + 1e-5f);
        const float4 gu = *(const float4*)(lnG + c4);
        const float4 bu = *(const float4*)(lnB + c4);
        ushort4 o4;
        o4.x = f2h((x.x-m)*rr*gu.x + bu.x);
        o4.y = f2h((x.y-m)*rr*gu.y + bu.y);
        o4.z = f2h((x.z-m)*rr*gu.z + bu.z);
        o4.w = f2h((x.w-m)*rr*gu.w + bu.w);
        *(ushort4*)(Lout + z*PLANE + (long)gm*256 + c4) = o4;
      } else if(headW){
        // fused head: identical reduction/code-path as the old k_head
        int d0 = c4;
        float a0 = x.x*headW[(d0+0)*3+0] + x.y*headW[(d0+1)*3+0] + x.z*headW[(d0+2)*3+0] + x.w*headW[(d0+3)*3+0];
        float a1 = x.x*headW[(d0+0)*3+1] + x.y*headW[(d0+1)*3+1] + x.z*headW[(d0+2)*3+1] + x.w*headW[(d0+3)*3+1];
        float a2 = x.x*headW[(d0+0)*3+2] + x.y*headW[(d0+1)*3+2] + x.z*headW[(d0+2)*3+2] + x.w*headW[(d0+3)*3+2];
        for(int o=1;o<64;o<<=1){
          a0 += __shfl_xor(a0,o); a1 += __shfl_xor(a1,o); a2 += __shfl_xor(a2,o);
        }
        if((t & 63)==0){
          float* op = headOut + ((long)z*NN + gm)*3;
          op[0] = a0 + headB[0];
          op[1] = a1 + headB[1];
          op[2] = a2 + headB[2];
        }
      }
    }
  }
}

// ------------- fused k+v spmm gather (fp16 planes, fp32 accum) -------------
// MODE 0: k+v gather+store, D-SPLIT via blockIdx.z (dhalf). Per-XCD-phase read
//   working set = k-half (2MB) + v-half (2MB) = 4MB = one XCD L2.
// MODE 1: z=0 -> rowdot rs = (q . gather(k))*INV6, full-D; z=1 -> v3 gather,
//   D-split by y.
template<int MODE>
__global__ __launch_bounds__(256) void k_spmm2(
    const u16* __restrict__ kin, const u16* __restrict__ vin,
    const int* __restrict__ offB, const int* __restrict__ srcB,
    u16* __restrict__ kout, u16* __restrict__ vout,
    const u16* __restrict__ q, float* __restrict__ rs){
  long z = blockIdx.x;
  const int* off = offB + z*(NN+1);
  const int* sE  = srcB + z*(long)NN*KK;

  if constexpr (MODE == 0){
    const u16* kp = kin + z*PLANE;
    const u16* vp = vin + z*PLANE;
    int row = blockIdx.y*16 + (threadIdx.x >> 4);
    int d8 = blockIdx.z*128 + (threadIdx.x & 15)*8;
    int s0 = off[row], s1 = off[row+1];
    float ak[8], av[8];
    #pragma unroll
    for(int j=0;j<8;j++){ ak[j]=0.f; av[j]=0.f; }
    int e = s0;
    for(; e+1 < s1; e += 2){
      int n0 = sE[e], n1 = sE[e+1];
      us8 k0 = *(const us8*)(kp + (long)n0*DD + d8);
      us8 k1 = *(const us8*)(kp + (long)n1*DD + d8);
      us8 v0 = *(const us8*)(vp + (long)n0*DD + d8);
      us8 v1 = *(const us8*)(vp + (long)n1*DD + d8);
      #pragma unroll
      for(int j=0;j<8;j++){
        ak[j] += h2f(k0[j]) + h2f(k1[j]);
        av[j] += h2f(v0[j]) + h2f(v1[j]);
      }
    }
    if(e < s1){
      int n0 = sE[e];
      us8 k0 = *(const us8*)(kp + (long)n0*DD + d8);
      us8 v0 = *(const us8*)(vp + (long)n0*DD + d8);
      #pragma unroll
      for(int j=0;j<8;j++){ ak[j] += h2f(k0[j]); av[j] += h2f(v0[j]); }
    }
    us8 ok, ov;
    #pragma unroll
    for(int j=0;j<8;j++){ ok[j] = f2h(ak[j]*INV6); ov[j] = f2h(av[j]*INV6); }
    *(us8*)(kout + z*PLANE + (long)row*DD + d8) = ok;
    *(us8*)(vout + z*PLANE + (long)row*DD + d8) = ov;
  } else {
    if(blockIdx.z == 0){
      const u16* kp = kin + z*PLANE;
      int row = blockIdx.y*8 + (threadIdx.x >> 5);
      int l32 = threadIdx.x & 31;
      int d8 = l32*8;
      int s0 = off[row], s1 = off[row+1];
      float ak[8];
      #pragma unroll
      for(int j=0;j<8;j++) ak[j]=0.f;
      int e = s0;
      for(; e+1 < s1; e += 2){
        int n0 = sE[e], n1 = sE[e+1];
        us8 k0 = *(const us8*)(kp + (long)n0*DD + d8);
        us8 k1 = *(const us8*)(kp + (long)n1*DD + d8);
        #pragma unroll
        for(int j=0;j<8;j++) ak[j] += h2f(k0[j]) + h2f(k1[j]);
      }
      if(e < s1){
        int n0 = sE[e];
        us8 k0 = *(const us8*)(kp + (long)n0*DD + d8);
        #pragma unroll
        for(int j=0;j<8;j++) ak[j] += h2f(k0[j]);
      }
      us8 qv = *(const us8*)(q + z*PLANE + (long)row*DD + d8);
      float s = 0.f;
      #pragma unroll
      for(int j=0;j<8;j++) s += h2f(qv[j]) * ak[j];
      for(int o=1;o<32;o<<=1) s += __shfl_xor(s,o);
      if(l32==0) rs[z*NN + row] = s*INV6;
    } else {
      const u16* vp = vin + z*PLANE;
      int row = (blockIdx.y & 511)*16 + (threadIdx.x >> 4);
      int d8 = (blockIdx.y >> 9)*128 + (threadIdx.x & 15)*8;
      int s0 = off[row], s1 = off[row+1];
      float av[8];
      #pragma unroll
      for(int j=0;j<8;j++) av[j]=0.f;
      int e = s0;
      for(; e+1 < s1; e += 2){
        int n0 = sE[e], n1 = sE[e+1];
        us8 v0 = *(const us8*)(vp + (long)n0*DD + d8);
        us8 v1 = *(const us8*)(vp + (long)n1*DD + d8);
        #pragma unroll
        for(int j=0;j<8;j++) av[j] += h2f(v0[j]) + h2f(v1[j]);
      }
      if(e < s1){
        int n0 = sE[e];
        us8 v0 = *(const us8*)(vp + (long)n0*DD + d8);
        #pragma unroll
        for(int j=0;j<8;j++) av[j] += h2f(v0[j]);
      }
      us8 ov;
      #pragma unroll
      for(int j=0;j<8;j++) ov[j] = f2h(av[j]*INV6);
      *(us8*)(vout + z*PLANE + (long)row*DD + d8) = ov;
    }
  }
}

struct Carve {
  float *h; u16 *L,*Q,*Bp,*Cp,*T;
  float *kvf; u16 *w2t;
  float *ksum,*rs;
  int *off,*cursor,*srcE;
  u16 *wt_gqkv,*wt_aqkv,*wt_gout,*wt_aout;
  size_t total;
};

static Carve carve(char* base, int C){
  Carve c;
  size_t cur = 0;
  auto bump = [&](size_t bytes)->char*{
    char* p = base ? base + cur : (char*)0;
    cur += (bytes + 255) & ~(size_t)255;
    return p;
  };
  c.h    = (float*)bump((size_t)C*PLANE*4);
  c.L    = (u16*)bump((size_t)C*PLANE*2);   // LN out
  c.Q    = (u16*)bump((size_t)C*PLANE*2);
  c.Bp   = (u16*)bump((size_t)C*PLANE*2);   // k / kT (attn)
  c.Cp   = (u16*)bump((size_t)C*PLANE*2);   // v
  c.T    = (u16*)bump((size_t)C*PLANE*2);   // v-hop pong / v3 / vT (attn)
  c.kvf  = (float*)bump((size_t)C*DD*DD*4);
  c.w2t  = (u16*)bump((size_t)C*2*DD*DD*2); // split pair
  c.ksum = (float*)bump((size_t)C*DD*4);
  c.rs   = (float*)bump((size_t)C*NN*4);
  c.off  = (int*)bump((size_t)BB*(NN+1)*4);
  c.cursor=(int*)bump((size_t)BB*(NN+1)*4);
  c.srcE = (int*)bump((size_t)NE*4);
  c.wt_gqkv = (u16*)bump((size_t)LL*2*768*256*2);
  c.wt_aqkv = (u16*)bump((size_t)LL*2*768*256*2);
  c.wt_gout = (u16*)bump((size_t)LL*2*256*256*2);
  c.wt_aout = (u16*)bump((size_t)LL*2*256*256*2);
  c.total = cur;
  return c;
}

extern "C" void kernel_launch(void* const* d_in, const int* in_sizes, int n_in,
                              void* d_out, int out_size, void* d_ws, size_t ws_size,
                              hipStream_t stream)
{
  const float* x        = (const float*)d_in[0];
  const int*   knn      = (const int*)d_in[1];
  const float* emb_w    = (const float*)d_in[2];
  const float* emb_b    = (const float*)d_in[3];
  const float* norm_g   = (const float*)d_in[4];
  const float* norm_b   = (const float*)d_in[5];
  const float* grf_qkv  = (const float*)d_in[6];
  const float* grf_outw = (const float*)d_in[7];
  const float* grf_outb = (const float*)d_in[8];
  const float* attn_qkv = (const float*)d_in[9];
  const float* attn_outw= (const float*)d_in[10];
  const float* attn_outb= (const float*)d_in[11];
  const float* head_w   = (const float*)d_in[12];
  const float* head_b   = (const float*)d_in[13];
  float* out = (float*)d_out;

  int C = 1;
  for(int cc=BB; cc>=1; cc>>=1){ if(carve(nullptr, cc).total <= ws_size){ C = cc; break; } }
  Carve ws = carve((char*)d_ws, C);

  // ---- weight prep (hi/lo fp16, transposed to [N][K]) ----
  k_prepw<<<dim3(768, LL), 256, 0, stream>>>(grf_qkv,  ws.wt_gqkv, 768);
  k_prepw<<<dim3(768, LL), 256, 0, stream>>>(attn_qkv, ws.wt_aqkv, 768);
  k_prepw<<<dim3(256, LL), 256, 0, stream>>>(grf_outw, ws.wt_gout, 256);
  k_prepw<<<dim3(256, LL), 256, 0, stream>>>(attn_outw,ws.wt_aout, 256);

  // ---- CSR build for all batches ----
  hipMemsetAsync(ws.off, 0, (size_t)BB*(NN+1)*sizeof(int), stream);
  k_count<<<dim3((NE+255)/256), 256, 0, stream>>>(knn, ws.off);
  k_scan<<<dim3(BB), 1024, 0, stream>>>(ws.off);
  hipMemcpyAsync(ws.cursor, ws.off, (size_t)BB*(NN+1)*sizeof(int), hipMemcpyDeviceToDevice, stream);
  k_fill<<<dim3((NE+255)/256), 256, 0, stream>>>(knn, ws.cursor, ws.srcE);

  const long PL = PLANE;
  for(int b0=0; b0<BB; b0+=C){
    const int* offB  = ws.off  + (long)b0*(NN+1);
    const int* srcB  = ws.srcE + (long)b0*NN*KK;

    k_embed<<<dim3(NN, C), 256, 0, stream>>>(x + (long)b0*NN*3, emb_w, emb_b, ws.h);
    k_ln<<<dim3(NN/4, C), 256, 0, stream>>>(ws.h, norm_g, norm_b, ws.L);

    for(int i=0; i<LL; i++){
      // ===== GRF sublayer =====
      k_mgemm<128,128,false,false,true><<<dim3(64, 6, C), 256, 0, stream>>>(
          ws.L, PL, 0, 256, 1,
          ws.wt_gqkv + (long)i*2*768*256, 0, (long)768*256,
          nullptr, 0, nullptr,
          ws.Q, ws.Bp, ws.Cp, PL, 0, 0, nullptr, 0,
          nullptr, nullptr, nullptr);
      k_spmm2<0><<<dim3(C, NN/16, 2), 256, 0, stream>>>(ws.Bp, ws.Cp, offB, srcB, ws.L, ws.T, nullptr, nullptr);
      k_spmm2<0><<<dim3(C, NN/16, 2), 256, 0, stream>>>(ws.L,  ws.T,  offB, srcB, ws.Bp, ws.Cp, nullptr, nullptr);
      k_spmm2<1><<<dim3(C, NN/8, 2), 256, 0, stream>>>(ws.Bp, ws.Cp, offB, srcB, nullptr, ws.T, ws.Q, ws.rs);
      // h += (rs*v3) @ grf_outw + grf_outb ; fused LN -> L (attn LN, norm 2i+1)
      k_fusedout<<<dim3(NN/32, 1, C), 256, 0, stream>>>(
          ws.T, ws.wt_gout + (long)i*2*256*256, 0, (long)256*256,
          ws.rs, nullptr, grf_outb + (long)i*DD, ws.h,
          norm_g + (2*i+1)*DD, norm_b + (2*i+1)*DD, ws.L,
          nullptr, nullptr, nullptr);

      // ===== linear attention sublayer =====
      // qkv: Q row-major; kT -> Bp, vT -> T written DIRECTLY TRANSPOSED from
      // acc (R12: deletes k_transp2 + dead row-major k/v planes); ksum fused.
      hipMemsetAsync(ws.ksum, 0, (size_t)C*DD*sizeof(float), stream);
      k_mgemm<128,128,false,false,true><<<dim3(64, 6, C), 256, 0, stream>>>(
          ws.L, PL, 0, 256, 1,
          ws.wt_aqkv + (long)i*2*768*256, 0, (long)768*256,
          nullptr, 0, nullptr,
          ws.Q, nullptr, nullptr, PL, 3 /* relu+1e-6 on q,k */, 0, nullptr, 0,
          ws.Bp, ws.T, ws.ksum);
      // kv[d][e] = sum_n kT[d][n] * vT[e][n]  (split-K=8, atomic fp32)
      hipMemsetAsync(ws.kvf, 0, (size_t)C*DD*DD*sizeof(float), stream);
      k_mgemm<64,64,false,false,false><<<dim3(4, 4, C*8), 256, 0, stream>>>(
          ws.Bp, PL, 0, NN, 8,
          ws.T, PL, 0,
          nullptr, 0, nullptr,
          nullptr, nullptr, nullptr, 0, 0, 0, ws.kvf, (long)DD*DD,
          nullptr, nullptr, nullptr);
      // w2t[n][d] = sum_e WoutT[n][e](split) * kv[d][e]  -> split fp16 pair
      k_mgemm<64,64,true,true,false><<<dim3(4, 4, C), 256, 0, stream>>>(
          ws.wt_aout + (long)i*2*256*256, 0, (long)256*256, 256, 1,
          ws.kvf, (long)DD*DD, 0,
          nullptr, 0, nullptr,
          ws.w2t, nullptr, nullptr, (long)DD*DD, 0, (long)DD*DD,
          nullptr, 0,
          nullptr, nullptr, nullptr);
      // h += (z*q) @ w2 + attn_outb ; rs inline from ksum; fused LN -> L,
      // or (last layer) fused head -> out
      const float* g2 = (i==LL-1) ? nullptr : norm_g + (2*i+2)*DD;
      const float* b2 = (i==LL-1) ? nullptr : norm_b + (2*i+2)*DD;
      k_fusedout<<<dim3(NN/32, 1, C), 256, 0, stream>>>(
          ws.Q, ws.w2t, 2L*DD*DD, (long)DD*DD,
          nullptr, ws.ksum, attn_outb + (long)i*DD, ws.h,
          g2, b2, ws.L,
          (i==LL-1) ? head_w : nullptr,
          (i==LL-1) ? head_b : nullptr,
          (i==LL-1) ? (out + (long)b0*NN*3) : nullptr);
    }
  }
}

// Round 13
// 2332.610 us; speedup vs baseline: 1.1801x; 1.0042x over previous
//
#include <hip/hip_runtime.h>

#define BB 8
#define NN 8192
#define KK 6
#define DD 256
#define LL 5
#define NE (BB*NN*KK)       // 393216
#define PLANE (NN*DD)       // 2097152 elems per batch
#define INV6 (1.0f/6.000001f)

typedef unsigned short u16;
typedef __attribute__((ext_vector_type(8))) _Float16 h8;
typedef __attribute__((ext_vector_type(8))) unsigned short us8;
typedef __attribute__((ext_vector_type(4))) float f32x4;

__device__ __forceinline__ u16 f2h(float f){
  union { _Float16 h; u16 u; } c; c.h = (_Float16)f; return c.u;
}
__device__ __forceinline__ float h2f(u16 u){
  union { _Float16 h; u16 u; } c; c.u = u; return (float)c.h;
}

// async global->LDS 16B copy: LDS dest must be wave-uniform base + lane*16
__device__ __forceinline__ void ldscp(const u16* g, u16* l){
  __builtin_amdgcn_global_load_lds(
      (const __attribute__((address_space(1))) void*)g,
      (__attribute__((address_space(3))) void*)l, 16, 0, 0);
}

// ---------------- CSR build ----------------
__global__ void k_count(const int* __restrict__ knn, int* __restrict__ off){
  int e = blockIdx.x*256 + threadIdx.x;
  if(e >= NE) return;
  int b = e / (NN*KK);
  int j = knn[e];
  atomicAdd(&off[b*(NN+1) + 1 + j], 1);
}

__global__ __launch_bounds__(1024) void k_scan(int* __restrict__ offAll){
  __shared__ int lds[1024];
  __shared__ int carry_s;
  int* off = offAll + blockIdx.x*(NN+1);
  const int len = NN+1;
  int t = threadIdx.x;
  if(t==0) carry_s = 0;
  __syncthreads();
  for(int base=0; base<len; base+=1024){
    int x = (base+t < len) ? off[base+t] : 0;
    lds[t] = x; __syncthreads();
    for(int s=1; s<1024; s<<=1){
      int v = (t>=s) ? lds[t-s] : 0;
      __syncthreads();
      lds[t] += v;
      __syncthreads();
    }
    int incl = lds[t];
    int carry = carry_s;
    __syncthreads();
    if(base+t < len) off[base+t] = incl + carry;
    if(t==1023) carry_s = carry + incl;
    __syncthreads();
  }
}

__global__ void k_fill(const int* __restrict__ knn, int* __restrict__ cursor, int* __restrict__ srcE){
  int e = blockIdx.x*256 + threadIdx.x;
  if(e >= NE) return;
  int b = e / (NN*KK);
  int n = (e % (NN*KK)) / KK;
  int j = knn[e];
  int pos = atomicAdd(&cursor[b*(NN+1) + j], 1);
  srcE[(long)b*NN*KK + pos] = n;
}

// ---- weight prep: W fp32 [L][256][N] -> Wt hi/lo fp16 [L][2][N][256] ----
__global__ __launch_bounds__(256) void k_prepw(const float* __restrict__ W, u16* __restrict__ Wt, int N){
  int n = blockIdx.x, l = blockIdx.y, k = threadIdx.x;
  float x = W[((long)l*256 + k)*N + n];
  u16 hb = f2h(x);
  Wt[(((long)l*2 + 0)*N + n)*256 + k] = hb;
  Wt[(((long)l*2 + 1)*N + n)*256 + k] = f2h(x - h2f(hb));
}

// ---------------- embed + layer-0 LN (R13 merge: deletes k_ln dispatch) ----------------
// Phase 1: each of 256 threads computes one h element of the row, stores to
// global h + LDS. Phase 2: wave 0 replicates k_ln's EXACT code (float4 per
// lane, 64-lane butterfly) reading from LDS -> bit-identical L output.
__global__ __launch_bounds__(256) void k_embedln(
    const float* __restrict__ x, const float* __restrict__ ew,
    const float* __restrict__ eb, const float* __restrict__ g,
    const float* __restrict__ bia, float* __restrict__ h, u16* __restrict__ out){
  __shared__ float rowbuf[256];
  int gr = blockIdx.x;
  long z = blockIdx.y;
  int d = threadIdx.x;
  const float* xp = x + ((long)z*NN + gr)*3;
  float v = xp[0]*ew[0*DD+d] + xp[1]*ew[1*DD+d] + xp[2]*ew[2*DD+d] + eb[d];
  h[z*PLANE + (long)gr*DD + d] = v;
  rowbuf[d] = v;
  __syncthreads();
  if(threadIdx.x < 64){
    int lane = threadIdx.x;
    const float4 xv = *(const float4*)&rowbuf[lane*4];
    float s  = xv.x + xv.y + xv.z + xv.w;
    float s2 = xv.x*xv.x + xv.y*xv.y + xv.z*xv.z + xv.w*xv.w;
    for(int o=1;o<64;o<<=1){ s += __shfl_xor(s,o); s2 += __shfl_xor(s2,o); }
    float m = s*(1.0f/256.0f);
    float var = s2*(1.0f/256.0f) - m*m;
    float r = rsqrtf(var + 1e-5f);
    const float4 gu = *(const float4*)(g + lane*4);
    const float4 bu = *(const float4*)(bia + lane*4);
    ushort4 o4;
    o4.x = f2h((xv.x-m)*r*gu.x + bu.x);
    o4.y = f2h((xv.y-m)*r*gu.y + bu.y);
    o4.z = f2h((xv.z-m)*r*gu.z + bu.z);
    o4.w = f2h((xv.w-m)*r*gu.w + bu.w);
    *(ushort4*)(out + z*PLANE + (long)gr*DD + lane*4) = o4;
  }
}

// ---------------- fp16 MFMA GEMM ----------------
// R8 dbuf stage-early/drain-late K-loop (!BF32). R12 transposed-output mode
// for attn qkv (o1T: k/v stored directly transposed from acc + fused ksum).
// R13: kvfZero != null -> blocks cooperatively zero kvf[z] before the K-loop
// (deletes the per-layer kvf memset dispatch; consumer is the NEXT dispatch).
template<int BM,int BN,bool ASPLIT,bool BF32,bool BSPLIT>
__global__ __launch_bounds__(256) void k_mgemm(
    const u16* __restrict__ A, long aStride, long aLoOff, int K, int kSplit,
    const void* __restrict__ Bv, long bStride, long bLoOff,
    const float* __restrict__ rowscale, long rsStride,
    const float* __restrict__ bias,
    u16* __restrict__ o0, u16* __restrict__ o1, u16* __restrict__ o2,
    long oStride, int reluMask, long oLoOff,
    float* __restrict__ accOut, long hStride,
    u16* __restrict__ o1T, u16* __restrict__ o2T, float* __restrict__ ksumOut,
    float* __restrict__ kvfZero)
{
  constexpr int WM = BM/2, WN = BN/2, MT = WM/16, NT = WN/16;
  constexpr int STG1 = BM*32*(ASPLIT?2:1) + BN*32*(BSPLIT?2:1);
  constexpr int STGT = BF32 ? STG1 : 2*STG1;      // dbuf for !BF32
  constexpr int EPI = (BM==128) ? 32*132*2 : 0;
  constexpr int SM  = (STGT > EPI) ? STGT : EPI;
  __shared__ __align__(16) u16 smem[SM];
  float* epi = (float*)smem;

  const int t = threadIdx.x;
  const int nz = blockIdx.z;
  const long z = nz / kSplit;
  const int chunk = nz % kSplit;
  const int kLen = K / kSplit, kLo = chunk * kLen;
  const int rowTile = blockIdx.x*BM, colTile = blockIdx.y*BN;
  const int l = t & 63, w = t >> 6;
  const int wr = w >> 1, wc = w & 1;
  const int lm = l & 15, kq = l >> 4;

  if(kvfZero){
    // zero this block's slice of kvf[z] (DD*DD floats per batch)
    const int nblk = gridDim.x * gridDim.y;
    int bid = blockIdx.x + gridDim.x*blockIdx.y;
    int S = (DD*DD + nblk - 1)/nblk;
    int st = bid*S;
    int en = st + S; if(en > DD*DD) en = DD*DD;
    for(int i = st + t; i < en; i += 256) kvfZero[z*(long)DD*DD + i] = 0.f;
  }

  f32x4 acc[MT][NT];
  #pragma unroll
  for(int mt=0;mt<MT;mt++)
    #pragma unroll
    for(int nt=0;nt<NT;nt++) acc[mt][nt] = (f32x4){0.f,0.f,0.f,0.f};

  if constexpr (!BF32){
    // ---- double-buffered pipelined K-loop (stage-early, drain-late) ----
    auto stageAB = [&](int buf, int k0){
      u16* Ahi_ = smem + (size_t)buf*STG1;
      u16* Alo_ = Ahi_ + BM*32;
      u16* Bhi_ = Ahi_ + BM*32*(ASPLIT?2:1);
      u16* Blo_ = Bhi_ + BN*32;
      {
        constexpr int NCH = BM/64;
        #pragma unroll
        for(int li=0; li<NCH; li++){
          int f = li*256 + t;
          int row = f>>2, c = (f&3)*8;
          const u16* gp = A + z*aStride + (long)(rowTile+row)*K + k0 + c;
          ldscp(gp, &Ahi_[f*8]);
          if constexpr (ASPLIT) ldscp(gp + aLoOff, &Alo_[f*8]);
        }
      }
      {
        constexpr int NCH = BN/64;
        #pragma unroll
        for(int li=0; li<NCH; li++){
          int f = li*256 + t;
          int row = f>>2, c = (f&3)*8;
          const u16* gp = (const u16*)Bv + z*bStride + (long)(colTile+row)*K + k0 + c;
          ldscp(gp, &Bhi_[f*8]);
          if constexpr (BSPLIT) ldscp(gp + bLoOff, &Blo_[f*8]);
        }
      }
    };

    const int nsteps = kLen >> 5;
    stageAB(0, kLo);
    __syncthreads();                 // drain initial stage
    int cur = 0;
    for(int ks=0; ks<nsteps; ++ks){
      if(ks+1 < nsteps) stageAB(cur^1, kLo + ((ks+1)<<5));   // prefetch next
      const u16* Ahi_ = smem + (size_t)cur*STG1;
      const u16* Alo_ = Ahi_ + BM*32;
      const u16* Bhi_ = Ahi_ + BM*32*(ASPLIT?2:1);
      const u16* Blo_ = Bhi_ + BN*32;
      h8 ah[MT], al[MT], bh[NT], bl[NT];
      #pragma unroll
      for(int mt=0;mt<MT;mt++){
        int idx = (wr*WM + mt*16 + lm)*32 + kq*8;
        ah[mt] = *(const h8*)&Ahi_[idx];
        if constexpr (ASPLIT) al[mt] = *(const h8*)&Alo_[idx];
      }
      #pragma unroll
      for(int nt=0;nt<NT;nt++){
        int idx = (wc*WN + nt*16 + lm)*32 + kq*8;
        bh[nt] = *(const h8*)&Bhi_[idx];
        if constexpr (BSPLIT) bl[nt] = *(const h8*)&Blo_[idx];
      }
      #pragma unroll
      for(int mt=0;mt<MT;mt++)
        #pragma unroll
        for(int nt=0;nt<NT;nt++){
          acc[mt][nt] = __builtin_amdgcn_mfma_f32_16x16x32_f16(ah[mt], bh[nt], acc[mt][nt], 0, 0, 0);
          if constexpr (BSPLIT)
            acc[mt][nt] = __builtin_amdgcn_mfma_f32_16x16x32_f16(ah[mt], bl[nt], acc[mt][nt], 0, 0, 0);
          if constexpr (ASPLIT)
            acc[mt][nt] = __builtin_amdgcn_mfma_f32_16x16x32_f16(al[mt], bh[nt], acc[mt][nt], 0, 0, 0);
        }
      __syncthreads();               // single full drain per step, after MFMA
      cur ^= 1;
    }
  } else {
    // ---- legacy single-buffer loop (BF32/w2t path) ----
    u16* Ahi = smem;
    u16* Alo = smem + BM*32;
    u16* Bhi = smem + BM*32*(ASPLIT?2:1);
    for(int k0=kLo; k0<kLo+kLen; k0+=32){
      __syncthreads();
      {
        constexpr int NCH = BM/64;
        #pragma unroll
        for(int li=0; li<NCH; li++){
          int f = li*256 + t;
          int row = f>>2, c = (f&3)*8;
          const u16* gp = A + z*aStride + (long)(rowTile+row)*K + k0 + c;
          ldscp(gp, &Ahi[f*8]);
          if constexpr (ASPLIT) ldscp(gp + aLoOff, &Alo[f*8]);
        }
      }
      {
        constexpr int NCH = BN/64;
        #pragma unroll
        for(int li=0; li<NCH; li++){
          int f = li*256 + t;
          int row = f>>2, c = (f&3)*8;
          const float* src = (const float*)Bv + z*bStride + (long)(colTile+row)*K + k0 + c;
          float4 v0 = ((const float4*)src)[0], v1 = ((const float4*)src)[1];
          us8 hv;
          hv[0]=f2h(v0.x); hv[1]=f2h(v0.y); hv[2]=f2h(v0.z); hv[3]=f2h(v0.w);
          hv[4]=f2h(v1.x); hv[5]=f2h(v1.y); hv[6]=f2h(v1.z); hv[7]=f2h(v1.w);
          *(us8*)&Bhi[f*8] = hv;
        }
      }
      __syncthreads();
      h8 ah[MT], al[MT], bh[NT];
      #pragma unroll
      for(int mt=0;mt<MT;mt++){
        int idx = (wr*WM + mt*16 + lm)*32 + kq*8;
        ah[mt] = *(const h8*)&Ahi[idx];
        if constexpr (ASPLIT) al[mt] = *(const h8*)&Alo[idx];
      }
      #pragma unroll
      for(int nt=0;nt<NT;nt++){
        int idx = (wc*WN + nt*16 + lm)*32 + kq*8;
        bh[nt] = *(const h8*)&Bhi[idx];
      }
      #pragma unroll
      for(int mt=0;mt<MT;mt++)
        #pragma unroll
        for(int nt=0;nt<NT;nt++){
          acc[mt][nt] = __builtin_amdgcn_mfma_f32_16x16x32_f16(ah[mt], bh[nt], acc[mt][nt], 0, 0, 0);
          if constexpr (ASPLIT)
            acc[mt][nt] = __builtin_amdgcn_mfma_f32_16x16x32_f16(al[mt], bh[nt], acc[mt][nt], 0, 0, 0);
        }
    }
  }

  if constexpr (BM == 128){
    const int sec = colTile >> 8;
    if(o1T && sec >= 1){
      // ---- R12 transposed store path (k/v sections of attn qkv) ----
      u16* oT = (sec==1) ? o1T : o2T;
      const bool relu = (reluMask >> sec) & 1;
      float kpart[NT];
      #pragma unroll
      for(int nt=0;nt<NT;nt++) kpart[nt] = 0.f;
      #pragma unroll
      for(int mt=0;mt<MT;mt++){
        #pragma unroll
        for(int nt=0;nt<NT;nt++){
          int gcs = (colTile & 255) + wc*WN + nt*16 + lm;
          int gmb = rowTile + wr*WM + mt*16 + kq*4;
          ushort4 o4;
          #pragma unroll
          for(int r=0;r<4;r++){
            float val = acc[mt][nt][r];
            if(relu) val = fmaxf(val, 0.f) + 1e-6f;
            u16 hv = f2h(val);
            ((u16*)&o4)[r] = hv;
            if(sec==1) kpart[nt] += h2f(hv);
          }
          *(ushort4*)(oT + z*oStride + (long)gcs*NN + gmb) = o4;
        }
      }
      if(sec==1 && ksumOut){
        #pragma unroll
        for(int nt=0;nt<NT;nt++){
          float p = kpart[nt];
          p += __shfl_xor(p, 16);
          p += __shfl_xor(p, 32);
          if(kq==0){
            int gcs = (colTile & 255) + wc*WN + nt*16 + lm;
            atomicAdd(&ksumOut[z*DD + gcs], p);
          }
        }
      }
    } else {
    u16* osec = (sec==0) ? o0 : ((sec==1) ? o1 : o2);
    const bool relu = (reluMask >> sec) & 1;
    #pragma unroll
    for(int mt=0;mt<MT;mt++){
      __syncthreads();
      #pragma unroll
      for(int r=0;r<4;r++){
        int gm = rowTile + wr*64 + mt*16 + kq*4 + r;
        float sc = rowscale ? rowscale[z*rsStride + gm] : 1.0f;
        int rl = wr*16 + kq*4 + r;
        #pragma unroll
        for(int nt=0;nt<NT;nt++)
          epi[rl*132 + wc*64 + nt*16 + lm] = acc[mt][nt][r]*sc;
      }
      __syncthreads();
      #pragma unroll
      for(int ss=0;ss<2;ss++){
        int s = ss*256 + t;
        int rl = s >> 4, sc8 = (s & 15)*8;
        int gm2 = rowTile + (rl>>4)*64 + mt*16 + (rl & 15);
        float v[8];
        #pragma unroll
        for(int j=0;j<8;j++) v[j] = epi[rl*132 + sc8 + j];
        if(bias){
          const float* bp = bias + colTile + sc8;
          #pragma unroll
          for(int j=0;j<8;j++) v[j] += bp[j];
        }
        if(accOut){
          float* hp = accOut + z*hStride + (long)gm2*256 + colTile + sc8;
          float4 h0 = ((float4*)hp)[0], h1 = ((float4*)hp)[1];
          h0.x += v[0]; h0.y += v[1]; h0.z += v[2]; h0.w += v[3];
          h1.x += v[4]; h1.y += v[5]; h1.z += v[6]; h1.w += v[7];
          ((float4*)hp)[0] = h0; ((float4*)hp)[1] = h1;
        } else {
          us8 o8;
          #pragma unroll
          for(int j=0;j<8;j++){
            float vv = v[j];
            if(relu) vv = fmaxf(vv, 0.f) + 1e-6f;
            o8[j] = f2h(vv);
          }
          *(us8*)(osec + z*oStride + (long)gm2*256 + ((colTile + sc8) & 255)) = o8;
        }
      }
    }
    }
  } else {
    #pragma unroll
    for(int mt=0;mt<MT;mt++){
      #pragma unroll
      for(int r=0;r<4;r++){
        int gm = rowTile + wr*WM + mt*16 + kq*4 + r;
        float sc = rowscale ? rowscale[z*rsStride + gm] : 1.0f;
        if(accOut){
          float* hp = accOut + z*hStride + (long)gm*256;
          if(kSplit > 1){
            #pragma unroll
            for(int nt=0;nt<NT;nt++){
              int gc = colTile + wc*WN + nt*16 + lm;
              atomicAdd(&hp[gc], acc[mt][nt][r]);
            }
          } else {
            #pragma unroll
            for(int nt=0;nt<NT;nt++){
              int gc = colTile + wc*WN + nt*16 + lm;
              hp[gc] += acc[mt][nt][r]*sc + (bias ? bias[gc] : 0.f);
            }
          }
        } else {
          #pragma unroll
          for(int nt=0;nt<NT;nt++){
            int gc = colTile + wc*WN + nt*16 + lm;
            int sec = gc >> 8;
            u16* o = (sec==0) ? o0 : ((sec==1) ? o1 : o2);
            float val = acc[mt][nt][r]*sc + (bias ? bias[gc] : 0.f);
            if((reluMask >> sec) & 1) val = fmaxf(val, 0.f) + 1e-6f;
            if(sec==0 && oLoOff){
              u16* oo = o0 + 2*z*oStride + (long)gm*256 + (gc & 255);
              u16 hb = f2h(val);
              oo[0] = hb;
              oo[oLoOff] = f2h(val - h2f(hb));
            } else {
              o[z*oStride + (long)gm*256 + (gc & 255)] = f2h(val);
            }
          }
        }
      }
    }
  }
}

// ---------------- fused out-projection: GEMM + h RMW + LN / zcalc / head ----------------
// R9 fusions: ksumIn (inline zcalc), headW (inline head).
// R13: ksumZero != null (GRF side, runs right before attn qkv) -> block 0
// zeros ksum[z] (deletes the per-layer ksum memset dispatch).
__global__ __launch_bounds__(256) void k_fusedout(
    const u16* __restrict__ A, const u16* __restrict__ B, long bStride, long bLoOff,
    const float* __restrict__ rowscale, const float* __restrict__ ksumIn,
    const float* __restrict__ bias,
    float* __restrict__ h,
    const float* __restrict__ lnG, const float* __restrict__ lnB,
    u16* __restrict__ Lout,
    const float* __restrict__ headW, const float* __restrict__ headB,
    float* __restrict__ headOut,
    float* __restrict__ ksumZero)
{
  // smem: Bh 256x32 + Bl 256x32 u16 = 32,768B; epilogue 16x260 f32 = 16,640B
  __shared__ __align__(16) u16 smem[16384];
  u16* Bh = smem;
  u16* Bl = smem + 8192;
  float* epi = (float*)smem;

  const int t = threadIdx.x;
  const long z = blockIdx.z;
  const int rowTile = blockIdx.x*32;
  const int l = t & 63, w = t >> 6;
  const int wr = w >> 1, wc = w & 1;
  const int lm = l & 15, kq = l >> 4;
  const u16* Ab = A + z*PLANE;
  const u16* Bb = B + z*bStride;

  if(ksumZero && blockIdx.x == 0 && t < DD) ksumZero[z*DD + t] = 0.f;

  f32x4 acc[8];
  #pragma unroll
  for(int nt=0;nt<8;nt++) acc[nt] = (f32x4){0.f,0.f,0.f,0.f};

  // prologue: lane's A row-fragment for all 8 k-steps (64 fp16 = 32 VGPR)
  h8 areg[8];
  {
    const u16* arow = Ab + (long)(rowTile + wr*16 + lm)*256 + kq*8;
    #pragma unroll
    for(int kk=0;kk<8;kk++) areg[kk] = *(const h8*)(arow + kk*32);
  }

  // fused zcalc: rs = 1/(q . ksum + 1e-6) from A-regs (A = q). Lane holds
  // 64 of the row's 256 elems; reduce over the kq quad (lane bits 4,5).
  float rsv = 0.f;
  if(ksumIn){
    const float* kb = ksumIn + z*DD;
    float s = 0.f;
    #pragma unroll
    for(int kk=0;kk<8;kk++){
      const float4 c0v = *(const float4*)(kb + kq*8 + kk*32);
      const float4 c1v = *(const float4*)(kb + kq*8 + kk*32 + 4);
      s += (float)areg[kk][0]*c0v.x + (float)areg[kk][1]*c0v.y
         + (float)areg[kk][2]*c0v.z + (float)areg[kk][3]*c0v.w
         + (float)areg[kk][4]*c1v.x + (float)areg[kk][5]*c1v.y
         + (float)areg[kk][6]*c1v.z + (float)areg[kk][7]*c1v.w;
    }
    s += __shfl_xor(s, 16);
    s += __shfl_xor(s, 32);
    rsv = 1.0f/(s + 1e-6f);
  }

  #pragma unroll
  for(int kk=0; kk<8; ++kk){
    __syncthreads();
    #pragma unroll
    for(int li=0; li<4; li++){   // B: 256x32 tile per buffer, 4 x 16B per thread
      int f = li*256 + t;
      int row = f>>2, c = (f&3)*8;
      const u16* gp = Bb + (long)row*256 + kk*32 + c;
      ldscp(gp, &Bh[f*8]);
      ldscp(gp + bLoOff, &Bl[f*8]);
    }
    __syncthreads();
    #pragma unroll
    for(int nt=0;nt<8;nt++){
      int idx = (wc*128 + nt*16 + lm)*32 + kq*8;
      const h8 bhf = *(const h8*)&Bh[idx];
      const h8 blf = *(const h8*)&Bl[idx];
      acc[nt] = __builtin_amdgcn_mfma_f32_16x16x32_f16(areg[kk], bhf, acc[nt], 0, 0, 0);
      acc[nt] = __builtin_amdgcn_mfma_f32_16x16x32_f16(areg[kk], blf, acc[nt], 0, 0, 0);
    }
  }

  // epilogue: 2 phases of 16 rows (wave wr==p owns phase p's accumulators)
  #pragma unroll
  for(int p=0;p<2;p++){
    __syncthreads();
    if(wr == p){   // wave-uniform guard (wr constant per wave) -> shfl safe
      #pragma unroll
      for(int r=0;r<4;r++){
        int rl = kq*4 + r;
        int gm = rowTile + p*16 + rl;
        float sc;
        if(ksumIn) sc = __shfl(rsv, kq*4 + r);   // rs of row p*16+kq*4+r
        else       sc = rowscale ? rowscale[z*NN + gm] : 1.0f;
        #pragma unroll
        for(int nt=0;nt<8;nt++)
          epi[rl*260 + wc*128 + nt*16 + lm] = acc[nt][r]*sc;
      }
    }
    __syncthreads();
    // store phase: one 64-lane wave per row, float4 per lane (k_ln-identical)
    #pragma unroll
    for(int ss=0;ss<4;ss++){
      int s = ss*256 + t;
      int rl = s >> 6;               // 0..15 (uniform per wave)
      int c4 = (s & 63)*4;           // lane*4
      int gm = rowTile + p*16 + rl;
      float4 e = *(float4*)&epi[rl*260 + c4];
      float4 x;
      x.x = e.x + bias[c4+0];
      x.y = e.y + bias[c4+1];
      x.z = e.z + bias[c4+2];
      x.w = e.w + bias[c4+3];
      float* hp = h + z*PLANE + (long)gm*256 + c4;
      float4 h0 = *(float4*)hp;
      x.x += h0.x; x.y += h0.y; x.z += h0.z; x.w += h0.w;
      *(float4*)hp = x;
      if(lnG){
        float sA = x.x + x.y + x.z + x.w;
        float s2 = x.x*x.x + x.y*x.y + x.z*x.z + x.w*x.w;
        for(int o=1;o<64;o<<=1){ sA += __shfl_xor(sA,o); s2 += __shfl_xor(s2,o); }
        float m = sA*(1.0f/256.0f);
        float var = s2*(1.0f/256.0f) - m*m;
        float rr = rsqrtf(var + 1e-5f);
        const float4 gu = *(const float4*)(lnG + c4);
        const float4 bu = *(const float4*)(lnB + c4);
        ushort4 o4;
        o4.x = f2h((x.x-m)*rr*gu.x + bu.x);
        o4.y = f2h((x.y-m)*rr*gu.y + bu.y);
        o4.z = f2h((x.z-m)*rr*gu.z + bu.z);
        o4.w = f2h((x.w-m)*rr*gu.w + bu.w);
        *(ushort4*)(Lout + z*PLANE + (long)gm*256 + c4) = o4;
      } else if(headW){
        // fused head: identical reduction/code-path as the old k_head
        int d0 = c4;
        float a0 = x.x*headW[(d0+0)*3+0] + x.y*headW[(d0+1)*3+0] + x.z*headW[(d0+2)*3+0] + x.w*headW[(d0+3)*3+0];
        float a1 = x.x*headW[(d0+0)*3+1] + x.y*headW[(d0+1)*3+1] + x.z*headW[(d0+2)*3+1] + x.w*headW[(d0+3)*3+1];
        float a2 = x.x*headW[(d0+0)*3+2] + x.y*headW[(d0+1)*3+2] + x.z*headW[(d0+2)*3+2] + x.w*headW[(d0+3)*3+2];
        for(int o=1;o<64;o<<=1){
          a0 += __shfl_xor(a0,o); a1 += __shfl_xor(a1,o); a2 += __shfl_xor(a2,o);
        }
        if((t & 63)==0){
          float* op = headOut + ((long)z*NN + gm)*3;
          op[0] = a0 + headB[0];
          op[1] = a1 + headB[1];
          op[2] = a2 + headB[2];
        }
      }
    }
  }
}

// ------------- fused k+v spmm gather (fp16 planes, fp32 accum) -------------
// MODE 0: k+v gather+store, D-SPLIT via blockIdx.z (dhalf). Per-XCD-phase read
//   working set = k-half (2MB) + v-half (2MB) = 4MB = one XCD L2.
// MODE 1: z=0 -> rowdot rs = (q . gather(k))*INV6, full-D; z=1 -> v3 gather,
//   D-split by y.
template<int MODE>
__global__ __launch_bounds__(256) void k_spmm2(
    const u16* __restrict__ kin, const u16* __restrict__ vin,
    const int* __restrict__ offB, const int* __restrict__ srcB,
    u16* __restrict__ kout, u16* __restrict__ vout,
    const u16* __restrict__ q, float* __restrict__ rs){
  long z = blockIdx.x;
  const int* off = offB + z*(NN+1);
  const int* sE  = srcB + z*(long)NN*KK;

  if constexpr (MODE == 0){
    const u16* kp = kin + z*PLANE;
    const u16* vp = vin + z*PLANE;
    int row = blockIdx.y*16 + (threadIdx.x >> 4);
    int d8 = blockIdx.z*128 + (threadIdx.x & 15)*8;
    int s0 = off[row], s1 = off[row+1];
    float ak[8], av[8];
    #pragma unroll
    for(int j=0;j<8;j++){ ak[j]=0.f; av[j]=0.f; }
    int e = s0;
    for(; e+1 < s1; e += 2){
      int n0 = sE[e], n1 = sE[e+1];
      us8 k0 = *(const us8*)(kp + (long)n0*DD + d8);
      us8 k1 = *(const us8*)(kp + (long)n1*DD + d8);
      us8 v0 = *(const us8*)(vp + (long)n0*DD + d8);
      us8 v1 = *(const us8*)(vp + (long)n1*DD + d8);
      #pragma unroll
      for(int j=0;j<8;j++){
        ak[j] += h2f(k0[j]) + h2f(k1[j]);
        av[j] += h2f(v0[j]) + h2f(v1[j]);
      }
    }
    if(e < s1){
      int n0 = sE[e];
      us8 k0 = *(const us8*)(kp + (long)n0*DD + d8);
      us8 v0 = *(const us8*)(vp + (long)n0*DD + d8);
      #pragma unroll
      for(int j=0;j<8;j++){ ak[j] += h2f(k0[j]); av[j] += h2f(v0[j]); }
    }
    us8 ok, ov;
    #pragma unroll
    for(int j=0;j<8;j++){ ok[j] = f2h(ak[j]*INV6); ov[j] = f2h(av[j]*INV6); }
    *(us8*)(kout + z*PLANE + (long)row*DD + d8) = ok;
    *(us8*)(vout + z*PLANE + (long)row*DD + d8) = ov;
  } else {
    if(blockIdx.z == 0){
      const u16* kp = kin + z*PLANE;
      int row = blockIdx.y*8 + (threadIdx.x >> 5);
      int l32 = threadIdx.x & 31;
      int d8 = l32*8;
      int s0 = off[row], s1 = off[row+1];
      float ak[8];
      #pragma unroll
      for(int j=0;j<8;j++) ak[j]=0.f;
      int e = s0;
      for(; e+1 < s1; e += 2){
        int n0 = sE[e], n1 = sE[e+1];
        us8 k0 = *(const us8*)(kp + (long)n0*DD + d8);
        us8 k1 = *(const us8*)(kp + (long)n1*DD + d8);
        #pragma unroll
        for(int j=0;j<8;j++) ak[j] += h2f(k0[j]) + h2f(k1[j]);
      }
      if(e < s1){
        int n0 = sE[e];
        us8 k0 = *(const us8*)(kp + (long)n0*DD + d8);
        #pragma unroll
        for(int j=0;j<8;j++) ak[j] += h2f(k0[j]);
      }
      us8 qv = *(const us8*)(q + z*PLANE + (long)row*DD + d8);
      float s = 0.f;
      #pragma unroll
      for(int j=0;j<8;j++) s += h2f(qv[j]) * ak[j];
      for(int o=1;o<32;o<<=1) s += __shfl_xor(s,o);
      if(l32==0) rs[z*NN + row] = s*INV6;
    } else {
      const u16* vp = vin + z*PLANE;
      int row = (blockIdx.y & 511)*16 + (threadIdx.x >> 4);
      int d8 = (blockIdx.y >> 9)*128 + (threadIdx.x & 15)*8;
      int s0 = off[row], s1 = off[row+1];
      float av[8];
      #pragma unroll
      for(int j=0;j<8;j++) av[j]=0.f;
      int e = s0;
      for(; e+1 < s1; e += 2){
        int n0 = sE[e], n1 = sE[e+1];
        us8 v0 = *(const us8*)(vp + (long)n0*DD + d8);
        us8 v1 = *(const us8*)(vp + (long)n1*DD + d8);
        #pragma unroll
        for(int j=0;j<8;j++) av[j] += h2f(v0[j]) + h2f(v1[j]);
      }
      if(e < s1){
        int n0 = sE[e];
        us8 v0 = *(const us8*)(vp + (long)n0*DD + d8);
        #pragma unroll
        for(int j=0;j<8;j++) av[j] += h2f(v0[j]);
      }
      us8 ov;
      #pragma unroll
      for(int j=0;j<8;j++) ov[j] = f2h(av[j]*INV6);
      *(us8*)(vout + z*PLANE + (long)row*DD + d8) = ov;
    }
  }
}

struct Carve {
  float *h; u16 *L,*Q,*Bp,*Cp,*T;
  float *kvf; u16 *w2t;
  float *ksum,*rs;
  int *off,*cursor,*srcE;
  u16 *wt_gqkv,*wt_aqkv,*wt_gout,*wt_aout;
  size_t total;
};

static Carve carve(char* base, int C){
  Carve c;
  size_t cur = 0;
  auto bump = [&](size_t bytes)->char*{
    char* p = base ? base + cur : (char*)0;
    cur += (bytes + 255) & ~(size_t)255;
    return p;
  };
  c.h    = (float*)bump((size_t)C*PLANE*4);
  c.L    = (u16*)bump((size_t)C*PLANE*2);   // LN out
  c.Q    = (u16*)bump((size_t)C*PLANE*2);
  c.Bp   = (u16*)bump((size_t)C*PLANE*2);   // k / kT (attn)
  c.Cp   = (u16*)bump((size_t)C*PLANE*2);   // v
  c.T    = (u16*)bump((size_t)C*PLANE*2);   // v-hop pong / v3 / vT (attn)
  c.kvf  = (float*)bump((size_t)C*DD*DD*4);
  c.w2t  = (u16*)bump((size_t)C*2*DD*DD*2); // split pair
  c.ksum = (float*)bump((size_t)C*DD*4);
  c.rs   = (float*)bump((size_t)C*NN*4);
  c.off  = (int*)bump((size_t)BB*(NN+1)*4);
  c.cursor=(int*)bump((size_t)BB*(NN+1)*4);
  c.srcE = (int*)bump((size_t)NE*4);
  c.wt_gqkv = (u16*)bump((size_t)LL*2*768*256*2);
  c.wt_aqkv = (u16*)bump((size_t)LL*2*768*256*2);
  c.wt_gout = (u16*)bump((size_t)LL*2*256*256*2);
  c.wt_aout = (u16*)bump((size_t)LL*2*256*256*2);
  c.total = cur;
  return c;
}

extern "C" void kernel_launch(void* const* d_in, const int* in_sizes, int n_in,
                              void* d_out, int out_size, void* d_ws, size_t ws_size,
                              hipStream_t stream)
{
  const float* x        = (const float*)d_in[0];
  const int*   knn      = (const int*)d_in[1];
  const float* emb_w    = (const float*)d_in[2];
  const float* emb_b    = (const float*)d_in[3];
  const float* norm_g   = (const float*)d_in[4];
  const float* norm_b   = (const float*)d_in[5];
  const float* grf_qkv  = (const float*)d_in[6];
  const float* grf_outw = (const float*)d_in[7];
  const float* grf_outb = (const float*)d_in[8];
  const float* attn_qkv = (const float*)d_in[9];
  const float* attn_outw= (const float*)d_in[10];
  const float* attn_outb= (const float*)d_in[11];
  const float* head_w   = (const float*)d_in[12];
  const float* head_b   = (const float*)d_in[13];
  float* out = (float*)d_out;

  int C = 1;
  for(int cc=BB; cc>=1; cc>>=1){ if(carve(nullptr, cc).total <= ws_size){ C = cc; break; } }
  Carve ws = carve((char*)d_ws, C);

  // ---- weight prep (hi/lo fp16, transposed to [N][K]) ----
  k_prepw<<<dim3(768, LL), 256, 0, stream>>>(grf_qkv,  ws.wt_gqkv, 768);
  k_prepw<<<dim3(768, LL), 256, 0, stream>>>(attn_qkv, ws.wt_aqkv, 768);
  k_prepw<<<dim3(256, LL), 256, 0, stream>>>(grf_outw, ws.wt_gout, 256);
  k_prepw<<<dim3(256, LL), 256, 0, stream>>>(attn_outw,ws.wt_aout, 256);

  // ---- CSR build for all batches ----
  hipMemsetAsync(ws.off, 0, (size_t)BB*(NN+1)*sizeof(int), stream);
  k_count<<<dim3((NE+255)/256), 256, 0, stream>>>(knn, ws.off);
  k_scan<<<dim3(BB), 1024, 0, stream>>>(ws.off);
  hipMemcpyAsync(ws.cursor, ws.off, (size_t)BB*(NN+1)*sizeof(int), hipMemcpyDeviceToDevice, stream);
  k_fill<<<dim3((NE+255)/256), 256, 0, stream>>>(knn, ws.cursor, ws.srcE);

  const long PL = PLANE;
  for(int b0=0; b0<BB; b0+=C){
    const int* offB  = ws.off  + (long)b0*(NN+1);
    const int* srcB  = ws.srcE + (long)b0*NN*KK;

    // embed + layer-0 LN merged (R13)
    k_embedln<<<dim3(NN, C), 256, 0, stream>>>(
        x + (long)b0*NN*3, emb_w, emb_b, norm_g, norm_b, ws.h, ws.L);

    for(int i=0; i<LL; i++){
      // ===== GRF sublayer =====
      k_mgemm<128,128,false,false,true><<<dim3(64, 6, C), 256, 0, stream>>>(
          ws.L, PL, 0, 256, 1,
          ws.wt_gqkv + (long)i*2*768*256, 0, (long)768*256,
          nullptr, 0, nullptr,
          ws.Q, ws.Bp, ws.Cp, PL, 0, 0, nullptr, 0,
          nullptr, nullptr, nullptr, nullptr);
      k_spmm2<0><<<dim3(C, NN/16, 2), 256, 0, stream>>>(ws.Bp, ws.Cp, offB, srcB, ws.L, ws.T, nullptr, nullptr);
      k_spmm2<0><<<dim3(C, NN/16, 2), 256, 0, stream>>>(ws.L,  ws.T,  offB, srcB, ws.Bp, ws.Cp, nullptr, nullptr);
      k_spmm2<1><<<dim3(C, NN/8, 2), 256, 0, stream>>>(ws.Bp, ws.Cp, offB, srcB, nullptr, ws.T, ws.Q, ws.rs);
      // h += (rs*v3) @ grf_outw + grf_outb ; fused LN -> L ; zero ksum (R13)
      k_fusedout<<<dim3(NN/32, 1, C), 256, 0, stream>>>(
          ws.T, ws.wt_gout + (long)i*2*256*256, 0, (long)256*256,
          ws.rs, nullptr, grf_outb + (long)i*DD, ws.h,
          norm_g + (2*i+1)*DD, norm_b + (2*i+1)*DD, ws.L,
          nullptr, nullptr, nullptr,
          ws.ksum);

      // ===== linear attention sublayer =====
      // qkv: Q row-major; kT -> Bp, vT -> T directly transposed (R12); ksum
      // fused; kvf zeroed cooperatively (R13, consumer is next dispatch).
      k_mgemm<128,128,false,false,true><<<dim3(64, 6, C), 256, 0, stream>>>(
          ws.L, PL, 0, 256, 1,
          ws.wt_aqkv + (long)i*2*768*256, 0, (long)768*256,
          nullptr, 0, nullptr,
          ws.Q, nullptr, nullptr, PL, 3 /* relu+1e-6 on q,k */, 0, nullptr, 0,
          ws.Bp, ws.T, ws.ksum, ws.kvf);
      // kv[d][e] = sum_n kT[d][n] * vT[e][n]  (split-K=8, atomic fp32)
      k_mgemm<64,64,false,false,false><<<dim3(4, 4, C*8), 256, 0, stream>>>(
          ws.Bp, PL, 0, NN, 8,
          ws.T, PL, 0,
          nullptr, 0, nullptr,
          nullptr, nullptr, nullptr, 0, 0, 0, ws.kvf, (long)DD*DD,
          nullptr, nullptr, nullptr, nullptr);
      // w2t[n][d] = sum_e WoutT[n][e](split) * kv[d][e]  -> split fp16 pair
      k_mgemm<64,64,true,true,false><<<dim3(4, 4, C), 256, 0, stream>>>(
          ws.wt_aout + (long)i*2*256*256, 0, (long)256*256, 256, 1,
          ws.kvf, (long)DD*DD, 0,
          nullptr, 0, nullptr,
          ws.w2t, nullptr, nullptr, (long)DD*DD, 0, (long)DD*DD,
          nullptr, 0,
          nullptr, nullptr, nullptr, nullptr);
      // h += (z*q) @ w2 + attn_outb ; rs inline from ksum; fused LN -> L,
      // or (last layer) fused head -> out
      const float* g2 = (i==LL-1) ? nullptr : norm_g + (2*i+2)*DD;
      const float* b2 = (i==LL-1) ? nullptr : norm_b + (2*i+2)*DD;
      k_fusedout<<<dim3(NN/32, 1, C), 256, 0, stream>>>(
          ws.Q, ws.w2t, 2L*DD*DD, (long)DD*DD,
          nullptr, ws.ksum, attn_outb + (long)i*DD, ws.h,
          g2, b2, ws.L,
          (i==LL-1) ? head_w : nullptr,
          (i==LL-1) ? head_b : nullptr,
          (i==LL-1) ? (out + (long)b0*NN*3) : nullptr,
          nullptr);
    }
  }
}